// Round 8
// baseline (377.496 us; speedup 1.0000x reference)
//
#include <hip/hip_runtime.h>
#include <math.h>

#define NN 20000
#define NPAD 20096   // 157*128 = 314*64: staging reads never go OOB
#define EE 320000
#define ET (EE + NN)

typedef __attribute__((ext_vector_type(8))) short bf16x8;
typedef __attribute__((ext_vector_type(4))) float f32x4;
typedef __attribute__((ext_vector_type(4))) unsigned short us4;
typedef __attribute__((ext_vector_type(8))) unsigned short us8;
typedef __attribute__((ext_vector_type(4))) float fx4;

__device__ inline unsigned short f2bf(float f) {
    union { float f; unsigned u; } x; x.f = f;
    unsigned u = x.u;
    return (unsigned short)((u + 0x7FFF + ((u >> 16) & 1)) >> 16);
}
__device__ inline float bf2f(unsigned short u) {
    union { unsigned u; float f; } x; x.u = (unsigned)u << 16; return x.f;
}

__device__ inline void storeC(float* C, size_t idx, float v) { C[idx] = v; }
__device__ inline void storeC(unsigned short* C, size_t idx, float v) { C[idx] = f2bf(v); }

// async 16B/lane global -> LDS (linear dest: wave base + lane*16)
__device__ inline void gload_lds16(const void* g, void* l) {
    __builtin_amdgcn_global_load_lds(
        (const __attribute__((address_space(1))) unsigned int*)g,
        (__attribute__((address_space(3))) unsigned int*)l, 16, 0, 0);
}

// bijective XCD-chunked swizzle (m204)
__device__ inline int xcd_swz(int orig, int nwg) {
    int q = nwg >> 3, r = nwg & 7;
    int xcd = orig & 7, loc = orig >> 3;
    return (xcd < r ? xcd * (q + 1) : r * (q + 1) + (xcd - r) * q) + loc;
}

// ---------------- pre-pass: weight transpose+convert, x convert ----------------
__global__ __launch_bounds__(256) void transpose_bf16(const float* __restrict__ W,
                                                      unsigned short* __restrict__ Wt,
                                                      int K, int N) {
    __shared__ float t[32][33];
    int k0 = blockIdx.x * 32, n0 = blockIdx.y * 32;
    int c = threadIdx.x & 31, r8 = threadIdx.x >> 5;
    #pragma unroll
    for (int i = 0; i < 4; i++)
        t[r8 + i * 8][c] = W[(size_t)(k0 + r8 + i * 8) * N + n0 + c];
    __syncthreads();
    #pragma unroll
    for (int i = 0; i < 4; i++)
        Wt[(size_t)(n0 + r8 + i * 8) * K + k0 + c] = f2bf(t[c][r8 + i * 8]);
}

__global__ void cvt_bf16_v4(const float* __restrict__ in, unsigned short* __restrict__ out, int n4) {
    int i = blockIdx.x * blockDim.x + threadIdx.x;
    if (i < n4) {
        fx4 v = *(const fx4*)(in + (size_t)i * 4);
        us4 s;
        #pragma unroll
        for (int j = 0; j < 4; j++) s[j] = f2bf(v[j]);
        *(us4*)(out + (size_t)i * 4) = s;
    }
}

// ---------------- CSR construction ----------------
__global__ void count_init(int* cnt) {
    int n = blockIdx.x * blockDim.x + threadIdx.x;
    if (n < NN) cnt[n] = 1;  // self-loop
}

__global__ void count_edges(const int* dst, int* cnt) {
    int e = blockIdx.x * blockDim.x + threadIdx.x;
    if (e < EE) atomicAdd(&cnt[dst[e]], 1);
}

__global__ void scan_kernel(const int* cnt, int* indptr, int* cursor) {
    __shared__ int part[1024];
    int tid = threadIdx.x;
    const int CH = 20;
    int base = tid * CH;
    int sum = 0;
    for (int i = 0; i < CH; i++) {
        int idx = base + i;
        if (idx < NN) sum += cnt[idx];
    }
    part[tid] = sum;
    __syncthreads();
    for (int off = 1; off < 1024; off <<= 1) {
        int v = (tid >= off) ? part[tid - off] : 0;
        __syncthreads();
        part[tid] += v;
        __syncthreads();
    }
    int run = (tid == 0) ? 0 : part[tid - 1];
    for (int i = 0; i < CH; i++) {
        int idx = base + i;
        if (idx < NN) {
            indptr[idx] = run;
            cursor[idx] = run;
            run += cnt[idx];
        }
    }
    if (tid == 1023) indptr[NN] = run;
}

__global__ void scatter_self(int* cursor, int* esrc) {
    int n = blockIdx.x * blockDim.x + threadIdx.x;
    if (n < NN) {
        int pos = atomicAdd(&cursor[n], 1);
        esrc[pos] = n;
    }
}

__global__ void scatter_edges(const int* src, const int* dst, int* cursor, int* esrc) {
    int e = blockIdx.x * blockDim.x + threadIdx.x;
    if (e < EE) {
        int pos = atomicAdd(&cursor[dst[e]], 1);
        esrc[pos] = src[e];
    }
}

// ---------------- single-shot GEMM for short K (<=256): stage ALL of K once ----------------
// C[M,N] = A[M,K]*Bt[N,K]^T (+bias)(+relu). BM=BN=64, 4 waves, wave owns 16 x 64.
template <int KTOT, typename TC>
__global__ __launch_bounds__(256) void sshot_gemm(
    const unsigned short* __restrict__ A, int lda,
    const unsigned short* __restrict__ Bt, int ldbt,
    TC* __restrict__ C, int ldc,
    int M, const float* __restrict__ bias, int relu, int nwgx)
{
    constexpr int LPR = KTOT / 8;     // lanes per row (16B slots per row)
    constexpr int RPC = 512 / KTOT;   // rows per 1KB chunk
    constexpr int NCH = KTOT / 8;     // chunks per matrix (64 rows)
    constexpr int NCHW = NCH / 4;     // chunks per wave
    constexpr int KC = KTOT / 32;     // MFMA k-steps
    __shared__ unsigned short Als[64 * KTOT];
    __shared__ unsigned short Bls[64 * KTOT];

    int swz = xcd_swz(blockIdx.x, gridDim.x);
    int bx = swz % nwgx, by = swz / nwgx;
    int row0 = by * 64, col0 = bx * 64;

    int tid = threadIdx.x;
    int lane = tid & 63, w = tid >> 6;
    int ric = lane / LPR, slot = lane % LPR;

    // stage entire A and B tiles
    #pragma unroll
    for (int i = 0; i < NCHW; i++) {
        int ch = w * NCHW + i;
        int r = ch * RPC + ric;
        gload_lds16(A + (size_t)(row0 + r) * lda + ((slot ^ (r & 7)) << 3),
                    &Als[ch * 512 + lane * 8]);
    }
    #pragma unroll
    for (int i = 0; i < NCHW; i++) {
        int ch = w * NCHW + i;
        int r = ch * RPC + ric;
        gload_lds16(Bt + (size_t)(col0 + r) * ldbt + ((slot ^ (r & 7)) << 3),
                    &Bls[ch * 512 + lane * 8]);
    }
    __syncthreads();   // drains vmcnt

    f32x4 acc[4];
    #pragma unroll
    for (int j = 0; j < 4; j++) acc[j] = (f32x4){0.f, 0.f, 0.f, 0.f};

    #pragma unroll
    for (int kc = 0; kc < KC; kc++) {
        int ks = (kc << 2) + (lane >> 4);
        int ra = (w << 4) + (lane & 15);
        bf16x8 af = *(bf16x8*)&Als[ra * KTOT + ((ks ^ (ra & 7)) << 3)];
        #pragma unroll
        for (int j = 0; j < 4; j++) {
            int rb = (j << 4) + (lane & 15);
            bf16x8 bf = *(bf16x8*)&Bls[rb * KTOT + ((ks ^ (rb & 7)) << 3)];
            acc[j] = __builtin_amdgcn_mfma_f32_16x16x32_bf16(af, bf, acc[j], 0, 0, 0);
        }
    }

    #pragma unroll
    for (int rr = 0; rr < 4; rr++) {
        int row = row0 + (w << 4) + ((lane >> 4) << 2) + rr;
        if (row >= M) continue;
        #pragma unroll
        for (int j = 0; j < 4; j++) {
            int col = col0 + j * 16 + (lane & 15);
            float v = acc[j][rr] + (bias ? bias[col] : 0.f);
            if (relu) v = fmaxf(v, 0.f);
            storeC(C, (size_t)row * ldc + col, v);
        }
    }
}

// ---------------- pipelined GEMM for long K: depth-2 prefetch, counted vmcnt ----------------
template <int BN, typename TC>
__global__ __launch_bounds__(256) void mfma_gemm(
    const unsigned short* __restrict__ A, int lda,
    const unsigned short* __restrict__ Bt, int ldbt,
    TC* __restrict__ C, int ldc,
    int M, int K,
    const float* __restrict__ bias, int relu, int nwgx)
{
    constexpr int BM = 128, BK = 64;
    constexpr int NJ = BN / 16;
    constexpr int NCHB = BN / 8;
    constexpr int PER_STAGE = 4 + NCHB / 4;   // gloads per wave per tile
    __shared__ unsigned short Als[2][BM * BK];
    __shared__ unsigned short Bls[2][BN * BK];

    int swz = xcd_swz(blockIdx.x, gridDim.x);
    int bx = swz % nwgx, by = swz / nwgx;

    int tid = threadIdx.x;
    int lane = tid & 63, w = tid >> 6;
    int row0 = by * BM, col0 = bx * BN;

    int lr = lane >> 3;
    int scol = ((lane & 7) ^ lr) << 3;

    f32x4 acc[2][NJ];
    #pragma unroll
    for (int i = 0; i < 2; i++)
        #pragma unroll
        for (int j = 0; j < NJ; j++) acc[i][j] = (f32x4){0.f, 0.f, 0.f, 0.f};

    auto stage = [&](int buf, int k0) {
        #pragma unroll
        for (int i = 0; i < 4; i++) {
            int ch = (w << 2) + i;
            gload_lds16(A + (size_t)(row0 + (ch << 3) + lr) * lda + k0 + scol,
                        &Als[buf][(ch << 9) + (lane << 3)]);
        }
        #pragma unroll
        for (int i = 0; i < NCHB / 4; i++) {
            int ch = w * (NCHB / 4) + i;
            gload_lds16(Bt + (size_t)(col0 + (ch << 3) + lr) * ldbt + k0 + scol,
                        &Bls[buf][(ch << 9) + (lane << 3)]);
        }
    };

    auto compute = [&](int buf) {
        #pragma unroll
        for (int kc = 0; kc < 2; kc++) {
            int ks = (kc << 2) + (lane >> 4);
            bf16x8 af[2];
            #pragma unroll
            for (int i = 0; i < 2; i++) {
                int rr = (w << 5) + (i << 4) + (lane & 15);
                af[i] = *(bf16x8*)&Als[buf][(rr << 6) + ((ks ^ (rr & 7)) << 3)];
            }
            bf16x8 bfr[NJ];
            #pragma unroll
            for (int j = 0; j < NJ; j++) {
                int rr = (j << 4) + (lane & 15);
                bfr[j] = *(bf16x8*)&Bls[buf][(rr << 6) + ((ks ^ (rr & 7)) << 3)];
            }
            #pragma unroll
            for (int i = 0; i < 2; i++)
                #pragma unroll
                for (int j = 0; j < NJ; j++)
                    acc[i][j] = __builtin_amdgcn_mfma_f32_16x16x32_bf16(af[i], bfr[j], acc[i][j], 0, 0, 0);
        }
    };

    int NT = K >> 6;
    stage(0, 0);
    stage(1, BK);
    for (int t = 0; t < NT; ++t) {
        if (t < NT - 1)
            asm volatile("s_waitcnt vmcnt(%0)" :: "i"(PER_STAGE) : "memory");
        else
            asm volatile("s_waitcnt vmcnt(0)" ::: "memory");
        __builtin_amdgcn_s_barrier();
        compute(t & 1);
        if (t + 2 < NT) {
            __builtin_amdgcn_s_barrier();   // all waves done reading buf[t&1]
            stage(t & 1, (t + 2) << 6);
        }
    }

    #pragma unroll
    for (int i = 0; i < 2; i++) {
        #pragma unroll
        for (int rr = 0; rr < 4; rr++) {
            int row = row0 + w * 32 + i * 16 + ((lane >> 4) << 2) + rr;
            if (row >= M) continue;
            #pragma unroll
            for (int j = 0; j < NJ; j++) {
                int col = col0 + j * 16 + (lane & 15);
                float v = acc[i][j][rr] + (bias ? bias[col] : 0.f);
                if (relu) v = fmaxf(v, 0.f);
                storeC(C, (size_t)row * ldc + col, v);
            }
        }
    }
}

// ---------------- attention logits: wave per node, 4 ch/lane ----------------
__global__ __launch_bounds__(256) void logits_kernel(
    const unsigned short* __restrict__ hbuf,
    const float* __restrict__ a_src, const float* __restrict__ a_dst,
    float* __restrict__ al, float* __restrict__ ar)
{
    int w = threadIdx.x >> 6;
    int n = blockIdx.x * 4 + w;
    if (n >= NN) return;
    int lane = threadIdx.x & 63;
    int c4 = lane * 4;
    us4 hv = *(const us4*)&hbuf[(size_t)n * 256 + c4];
    fx4 asv = *(const fx4*)&a_src[c4];
    fx4 adv = *(const fx4*)&a_dst[c4];
    float ps = 0.f, pd = 0.f;
    #pragma unroll
    for (int k = 0; k < 4; k++) {
        float h = bf2f(hv[k]);
        ps += h * asv[k];
        pd += h * adv[k];
    }
    #pragma unroll
    for (int off = 8; off; off >>= 1) {
        ps += __shfl_xor(ps, off);
        pd += __shfl_xor(pd, off);
    }
    if ((lane & 15) == 0) {
        al[n * 4 + (lane >> 4)] = ps;
        ar[n * 4 + (lane >> 4)] = pd;
    }
}

// ---------------- GAT aggregation: wave per node, 4 ch/lane, unroll-4 ----------------
__global__ __launch_bounds__(256) void aggregate_kernel(
    const unsigned short* __restrict__ hbuf,
    const float* __restrict__ al, const float* __restrict__ ar,
    const int* __restrict__ indptr, const int* __restrict__ esrc,
    const float* __restrict__ bias,
    unsigned short* __restrict__ out, int ldo)
{
    int w = threadIdx.x >> 6;
    int n = blockIdx.x * 4 + w;
    if (n >= NN) return;
    int lane = threadIdx.x & 63;
    int myh = lane >> 4;
    int c4 = lane * 4;
    int beg = indptr[n], end = indptr[n + 1];

    fx4 arn = *(const fx4*)&ar[(size_t)n * 4];

    fx4 mv = (fx4){-1e30f, -1e30f, -1e30f, -1e30f};
    for (int j = beg + lane; j < end; j += 64) {
        fx4 a = *(const fx4*)&al[(size_t)esrc[j] * 4];
        #pragma unroll
        for (int h = 0; h < 4; h++) {
            float e = a[h] + arn[h];
            e = e > 0.f ? e : 0.2f * e;
            mv[h] = fmaxf(mv[h], e);
        }
    }
    #pragma unroll
    for (int off = 32; off; off >>= 1) {
        #pragma unroll
        for (int h = 0; h < 4; h++) mv[h] = fmaxf(mv[h], __shfl_xor(mv[h], off));
    }
    float m = mv[myh];
    float arh = arn[myh];

    float ssum = 0.f;
    fx4 acc = (fx4){0.f, 0.f, 0.f, 0.f};
    int j = beg;
    for (; j + 4 <= end; j += 4) {
        int s0 = esrc[j], s1 = esrc[j + 1], s2 = esrc[j + 2], s3 = esrc[j + 3];
        us4 h0 = *(const us4*)&hbuf[(size_t)s0 * 256 + c4];
        us4 h1 = *(const us4*)&hbuf[(size_t)s1 * 256 + c4];
        us4 h2 = *(const us4*)&hbuf[(size_t)s2 * 256 + c4];
        us4 h3 = *(const us4*)&hbuf[(size_t)s3 * 256 + c4];
        float a0 = al[(size_t)s0 * 4 + myh];
        float a1 = al[(size_t)s1 * 4 + myh];
        float a2 = al[(size_t)s2 * 4 + myh];
        float a3 = al[(size_t)s3 * 4 + myh];
        float e0 = a0 + arh; e0 = e0 > 0.f ? e0 : 0.2f * e0;
        float e1 = a1 + arh; e1 = e1 > 0.f ? e1 : 0.2f * e1;
        float e2 = a2 + arh; e2 = e2 > 0.f ? e2 : 0.2f * e2;
        float e3 = a3 + arh; e3 = e3 > 0.f ? e3 : 0.2f * e3;
        float x0 = __expf(e0 - m), x1 = __expf(e1 - m);
        float x2 = __expf(e2 - m), x3 = __expf(e3 - m);
        ssum += x0 + x1 + x2 + x3;
        #pragma unroll
        for (int k = 0; k < 4; k++)
            acc[k] += x0 * bf2f(h0[k]) + x1 * bf2f(h1[k])
                    + x2 * bf2f(h2[k]) + x3 * bf2f(h3[k]);
    }
    for (; j < end; j++) {
        int s = esrc[j];
        us4 hv = *(const us4*)&hbuf[(size_t)s * 256 + c4];
        float a = al[(size_t)s * 4 + myh];
        float e = a + arh; e = e > 0.f ? e : 0.2f * e;
        float ex = __expf(e - m);
        ssum += ex;
        #pragma unroll
        for (int k = 0; k < 4; k++) acc[k] += ex * bf2f(hv[k]);
    }

    float inv = 1.f / (ssum + 1e-16f);
    us4 o;
    #pragma unroll
    for (int k = 0; k < 4; k++) o[k] = f2bf(acc[k] * inv + bias[c4 + k]);
    *(us4*)&out[(size_t)n * ldo + c4] = o;
}

// ---------------- output gathers (vectorized) ----------------
__global__ void gather_feats(const float* __restrict__ Bf, const float* __restrict__ Tf,
                             const int* __restrict__ voc, const int* __restrict__ batch,
                             float* __restrict__ out)
{
    int i = blockIdx.x * blockDim.x + threadIdx.x;
    if (i < NN * 32) {
        int n = i >> 5, c4 = (i & 31) * 4;
        int t = voc[n];
        *(fx4*)&out[(size_t)n * 128 + c4] = *(const fx4*)&Bf[(size_t)t * 128 + c4];
        *(fx4*)&out[(size_t)NN * 128 + (size_t)n * 128 + c4] = *(const fx4*)&Tf[(size_t)t * 128 + c4];
    }
    if (i < NN) out[(size_t)NN * 128 * 2 + (size_t)NN * 64 + i] = (float)batch[i];
}

// ---------------- host-side orchestration ----------------
extern "C" void kernel_launch(void* const* d_in, const int* in_sizes, int n_in,
                              void* d_out, int out_size, void* d_ws, size_t ws_size,
                              hipStream_t stream) {
    const float* x     = (const float*)d_in[0];
    const int*   ei    = (const int*)d_in[1];
    const int*   batch = (const int*)d_in[2];
    const int*   voc   = (const int*)d_in[3];
    const float* Bf    = (const float*)d_in[4];
    const float* Tf    = (const float*)d_in[5];
    const float* W0    = (const float*)d_in[6];
    const float* as0   = (const float*)d_in[7];
    const float* ad0   = (const float*)d_in[8];
    const float* b0    = (const float*)d_in[9];
    const float* W1    = (const float*)d_in[10];
    const float* as1   = (const float*)d_in[11];
    const float* ad1   = (const float*)d_in[12];
    const float* b1    = (const float*)d_in[13];
    const float* W2    = (const float*)d_in[14];
    const float* as2   = (const float*)d_in[15];
    const float* ad2   = (const float*)d_in[16];
    const float* b2    = (const float*)d_in[17];
    const float* fcmax_w = (const float*)d_in[18];
    const float* fcmax_b = (const float*)d_in[19];
    const float* fc1_w = (const float*)d_in[20];
    const float* fc1_b = (const float*)d_in[21];
    const float* fc2_w = (const float*)d_in[22];
    const float* fc2_b = (const float*)d_in[23];
    const float* fc3_w = (const float*)d_in[24];
    const float* fc3_b = (const float*)d_in[25];
    float* out = (float*)d_out;

    char* p = (char*)d_ws;
    unsigned short* xb  = (unsigned short*)p; p += (size_t)NPAD * 128 * 2;
    unsigned short* hbuf= (unsigned short*)p; p += (size_t)NN * 256 * 2;
    unsigned short* z   = (unsigned short*)p; p += (size_t)NPAD * 1536 * 2;
    unsigned short* z1  = (unsigned short*)p; p += (size_t)NPAD * 512 * 2;
    unsigned short* h2  = (unsigned short*)p; p += (size_t)NPAD * 128 * 2;
    unsigned short* w0t = (unsigned short*)p; p += (size_t)128 * 256 * 2;
    unsigned short* w1t = (unsigned short*)p; p += (size_t)256 * 256 * 2;
    unsigned short* w2t = (unsigned short*)p; p += (size_t)256 * 256 * 2;
    unsigned short* wmt = (unsigned short*)p; p += (size_t)256 * 256 * 2;
    unsigned short* f1t = (unsigned short*)p; p += (size_t)1536 * 512 * 2;
    unsigned short* f2t = (unsigned short*)p; p += (size_t)512 * 128 * 2;
    unsigned short* f3t = (unsigned short*)p; p += (size_t)128 * 64 * 2;
    float* al   = (float*)p; p += (size_t)NN * 4 * 4;
    float* ar   = (float*)p; p += (size_t)NN * 4 * 4;
    int* cnt    = (int*)p;   p += (size_t)NN * 4;
    int* cursor = (int*)p;   p += (size_t)NN * 4;
    int* esrc   = (int*)p;   p += (size_t)ET * 4;
    int* indptr = (int*)p;   p += (size_t)(NN + 1) * 4;

    const int* e_src = ei;
    const int* e_dst = ei + EE;

    // ---- pre-pass: weights -> bf16 transposed, x -> bf16 ----
    transpose_bf16<<<dim3(4, 8),  256, 0, stream>>>(W0, w0t, 128, 256);
    transpose_bf16<<<dim3(8, 8),  256, 0, stream>>>(W1, w1t, 256, 256);
    transpose_bf16<<<dim3(8, 8),  256, 0, stream>>>(W2, w2t, 256, 256);
    transpose_bf16<<<dim3(8, 8),  256, 0, stream>>>(fcmax_w, wmt, 256, 256);
    transpose_bf16<<<dim3(48, 16),256, 0, stream>>>(fc1_w, f1t, 1536, 512);
    transpose_bf16<<<dim3(16, 4), 256, 0, stream>>>(fc2_w, f2t, 512, 128);
    transpose_bf16<<<dim3(4, 2),  256, 0, stream>>>(fc3_w, f3t, 128, 64);
    cvt_bf16_v4<<<(NN * 32 + 255) / 256, 256, 0, stream>>>(x, xb, NN * 32);

    // ---- CSR (dst-sorted incoming edges, incl. self-loops) ----
    count_init<<<(NN + 255) / 256, 256, 0, stream>>>(cnt);
    count_edges<<<(EE + 255) / 256, 256, 0, stream>>>(e_dst, cnt);
    scan_kernel<<<1, 1024, 0, stream>>>(cnt, indptr, cursor);
    scatter_self<<<(NN + 255) / 256, 256, 0, stream>>>(cursor, esrc);
    scatter_edges<<<(EE + 255) / 256, 256, 0, stream>>>(e_src, e_dst, cursor, esrc);

    // ---- independent output gathers ----
    gather_feats<<<(NN * 32 + 255) / 256, 256, 0, stream>>>(Bf, Tf, voc, batch, out);

    const int MB = NPAD / 128;   // 157 (BM=128 pipelined)
    const int SB = NPAD / 64;    // 314 (BM=64 single-shot)
    const int NB4 = (NN + 3) / 4;

    // ---- GAT layer 0 ----
    sshot_gemm<128, unsigned short><<<4 * SB, 256, 0, stream>>>(xb, 128, w0t, 128, hbuf, 256, NN, nullptr, 0, 4);
    logits_kernel<<<NB4, 256, 0, stream>>>(hbuf, as0, ad0, al, ar);
    aggregate_kernel<<<NB4, 256, 0, stream>>>(hbuf, al, ar, indptr, esrc, b0, z + 0, 1536);
    sshot_gemm<256, unsigned short><<<4 * SB, 256, 0, stream>>>(z + 0, 1536, wmt, 256, z + 256, 1536, NN, fcmax_b, 1, 4);

    // ---- GAT layer 1 ----
    sshot_gemm<256, unsigned short><<<4 * SB, 256, 0, stream>>>(z + 256, 1536, w1t, 256, hbuf, 256, NN, nullptr, 0, 4);
    logits_kernel<<<NB4, 256, 0, stream>>>(hbuf, as1, ad1, al, ar);
    aggregate_kernel<<<NB4, 256, 0, stream>>>(hbuf, al, ar, indptr, esrc, b1, z + 512, 1536);
    sshot_gemm<256, unsigned short><<<4 * SB, 256, 0, stream>>>(z + 512, 1536, wmt, 256, z + 768, 1536, NN, fcmax_b, 1, 4);

    // ---- GAT layer 2 ----
    sshot_gemm<256, unsigned short><<<4 * SB, 256, 0, stream>>>(z + 768, 1536, w2t, 256, hbuf, 256, NN, nullptr, 0, 4);
    logits_kernel<<<NB4, 256, 0, stream>>>(hbuf, as2, ad2, al, ar);
    aggregate_kernel<<<NB4, 256, 0, stream>>>(hbuf, al, ar, indptr, esrc, b2, z + 1024, 1536);
    sshot_gemm<256, unsigned short><<<4 * SB, 256, 0, stream>>>(z + 1024, 1536, wmt, 256, z + 1280, 1536, NN, fcmax_b, 1, 4);

    // ---- MLP head ----
    mfma_gemm<128, unsigned short><<<4 * MB, 256, 0, stream>>>(z, 1536, f1t, 1536, z1, 512, NN, 1536, fc1_b, 1, 4);
    mfma_gemm<64, unsigned short><<<2 * MB, 256, 0, stream>>>(z1, 512, f2t, 512, h2, 128, NN, 512, fc2_b, 1, 2);
    sshot_gemm<128, float><<<1 * SB, 256, 0, stream>>>(h2, 128, f3t, 128, out + (size_t)2 * NN * 128, 64, NN, fc3_b, 0, 1);
}

// Round 9
// 360.876 us; speedup vs baseline: 1.0461x; 1.0461x over previous
//
#include <hip/hip_runtime.h>
#include <math.h>

#define NN 20000
#define NPAD 20096   // 157*128 = 314*64: staging reads never go OOB
#define EE 320000
#define ET (EE + NN)

typedef __attribute__((ext_vector_type(8))) short bf16x8;
typedef __attribute__((ext_vector_type(4))) float f32x4;
typedef __attribute__((ext_vector_type(4))) unsigned short us4;
typedef __attribute__((ext_vector_type(8))) unsigned short us8;
typedef __attribute__((ext_vector_type(4))) float fx4;

__device__ inline unsigned short f2bf(float f) {
    union { float f; unsigned u; } x; x.f = f;
    unsigned u = x.u;
    return (unsigned short)((u + 0x7FFF + ((u >> 16) & 1)) >> 16);
}
__device__ inline float bf2f(unsigned short u) {
    union { unsigned u; float f; } x; x.u = (unsigned)u << 16; return x.f;
}

__device__ inline void storeC(float* C, size_t idx, float v) { C[idx] = v; }
__device__ inline void storeC(unsigned short* C, size_t idx, float v) { C[idx] = f2bf(v); }

// async 16B/lane global -> LDS (linear dest: wave base + lane*16)
__device__ inline void gload_lds16(const void* g, void* l) {
    __builtin_amdgcn_global_load_lds(
        (const __attribute__((address_space(1))) unsigned int*)g,
        (__attribute__((address_space(3))) unsigned int*)l, 16, 0, 0);
}

// bijective XCD-chunked swizzle (m204)
__device__ inline int xcd_swz(int orig, int nwg) {
    int q = nwg >> 3, r = nwg & 7;
    int xcd = orig & 7, loc = orig >> 3;
    return (xcd < r ? xcd * (q + 1) : r * (q + 1) + (xcd - r) * q) + loc;
}

// ---------------- pre-pass: weight transpose+convert, x convert ----------------
__global__ __launch_bounds__(256) void transpose_bf16(const float* __restrict__ W,
                                                      unsigned short* __restrict__ Wt,
                                                      int K, int N) {
    __shared__ float t[32][33];
    int k0 = blockIdx.x * 32, n0 = blockIdx.y * 32;
    int c = threadIdx.x & 31, r8 = threadIdx.x >> 5;
    #pragma unroll
    for (int i = 0; i < 4; i++)
        t[r8 + i * 8][c] = W[(size_t)(k0 + r8 + i * 8) * N + n0 + c];
    __syncthreads();
    #pragma unroll
    for (int i = 0; i < 4; i++)
        Wt[(size_t)(n0 + r8 + i * 8) * K + k0 + c] = f2bf(t[c][r8 + i * 8]);
}

__global__ void cvt_bf16_v4(const float* __restrict__ in, unsigned short* __restrict__ out, int n4) {
    int i = blockIdx.x * blockDim.x + threadIdx.x;
    if (i < n4) {
        fx4 v = *(const fx4*)(in + (size_t)i * 4);
        us4 s;
        #pragma unroll
        for (int j = 0; j < 4; j++) s[j] = f2bf(v[j]);
        *(us4*)(out + (size_t)i * 4) = s;
    }
}

// ---------------- CSR construction ----------------
__global__ void count_init(int* cnt) {
    int n = blockIdx.x * blockDim.x + threadIdx.x;
    if (n < NN) cnt[n] = 1;  // self-loop
}

__global__ void count_edges(const int* dst, int* cnt) {
    int e = blockIdx.x * blockDim.x + threadIdx.x;
    if (e < EE) atomicAdd(&cnt[dst[e]], 1);
}

__global__ void scan_kernel(const int* cnt, int* indptr, int* cursor) {
    __shared__ int part[1024];
    int tid = threadIdx.x;
    const int CH = 20;
    int base = tid * CH;
    int sum = 0;
    for (int i = 0; i < CH; i++) {
        int idx = base + i;
        if (idx < NN) sum += cnt[idx];
    }
    part[tid] = sum;
    __syncthreads();
    for (int off = 1; off < 1024; off <<= 1) {
        int v = (tid >= off) ? part[tid - off] : 0;
        __syncthreads();
        part[tid] += v;
        __syncthreads();
    }
    int run = (tid == 0) ? 0 : part[tid - 1];
    for (int i = 0; i < CH; i++) {
        int idx = base + i;
        if (idx < NN) {
            indptr[idx] = run;
            cursor[idx] = run;
            run += cnt[idx];
        }
    }
    if (tid == 1023) indptr[NN] = run;
}

__global__ void scatter_self(int* cursor, int* esrc) {
    int n = blockIdx.x * blockDim.x + threadIdx.x;
    if (n < NN) {
        int pos = atomicAdd(&cursor[n], 1);
        esrc[pos] = n;
    }
}

__global__ void scatter_edges(const int* src, const int* dst, int* cursor, int* esrc) {
    int e = blockIdx.x * blockDim.x + threadIdx.x;
    if (e < EE) {
        int pos = atomicAdd(&cursor[dst[e]], 1);
        esrc[pos] = src[e];
    }
}

// ---------------- single-shot GEMM (fc3 only: N=64, K=128) ----------------
template <int KTOT, typename TC>
__global__ __launch_bounds__(256) void sshot_gemm(
    const unsigned short* __restrict__ A, int lda,
    const unsigned short* __restrict__ Bt, int ldbt,
    TC* __restrict__ C, int ldc,
    int M, const float* __restrict__ bias, int relu, int nwgx)
{
    constexpr int LPR = KTOT / 8;
    constexpr int RPC = 512 / KTOT;
    constexpr int NCH = KTOT / 8;
    constexpr int NCHW = NCH / 4;
    constexpr int KC = KTOT / 32;
    __shared__ unsigned short Als[64 * KTOT];
    __shared__ unsigned short Bls[64 * KTOT];

    int swz = xcd_swz(blockIdx.x, gridDim.x);
    int bx = swz % nwgx, by = swz / nwgx;
    int row0 = by * 64, col0 = bx * 64;

    int tid = threadIdx.x;
    int lane = tid & 63, w = tid >> 6;
    int ric = lane / LPR, slot = lane % LPR;

    #pragma unroll
    for (int i = 0; i < NCHW; i++) {
        int ch = w * NCHW + i;
        int r = ch * RPC + ric;
        gload_lds16(A + (size_t)(row0 + r) * lda + ((slot ^ (r & 7)) << 3),
                    &Als[ch * 512 + lane * 8]);
    }
    #pragma unroll
    for (int i = 0; i < NCHW; i++) {
        int ch = w * NCHW + i;
        int r = ch * RPC + ric;
        gload_lds16(Bt + (size_t)(col0 + r) * ldbt + ((slot ^ (r & 7)) << 3),
                    &Bls[ch * 512 + lane * 8]);
    }
    __syncthreads();

    f32x4 acc[4];
    #pragma unroll
    for (int j = 0; j < 4; j++) acc[j] = (f32x4){0.f, 0.f, 0.f, 0.f};

    #pragma unroll
    for (int kc = 0; kc < KC; kc++) {
        int ks = (kc << 2) + (lane >> 4);
        int ra = (w << 4) + (lane & 15);
        bf16x8 af = *(bf16x8*)&Als[ra * KTOT + ((ks ^ (ra & 7)) << 3)];
        #pragma unroll
        for (int j = 0; j < 4; j++) {
            int rb = (j << 4) + (lane & 15);
            bf16x8 bf = *(bf16x8*)&Bls[rb * KTOT + ((ks ^ (rb & 7)) << 3)];
            acc[j] = __builtin_amdgcn_mfma_f32_16x16x32_bf16(af, bf, acc[j], 0, 0, 0);
        }
    }

    #pragma unroll
    for (int rr = 0; rr < 4; rr++) {
        int row = row0 + (w << 4) + ((lane >> 4) << 2) + rr;
        if (row >= M) continue;
        #pragma unroll
        for (int j = 0; j < 4; j++) {
            int col = col0 + j * 16 + (lane & 15);
            float v = acc[j][rr] + (bias ? bias[col] : 0.f);
            if (relu) v = fmaxf(v, 0.f);
            storeC(C, (size_t)row * ldc + col, v);
        }
    }
}

// ---------------- pipelined GEMM: depth-2 counted vmcnt, 2D wave grid ----------------
// BN=128 -> 2x2 waves (tile 64x64); BN=64 -> 4x1 waves (tile 32x64)
template <int BN, typename TC>
__global__ __launch_bounds__(256) void mfma_gemm(
    const unsigned short* __restrict__ A, int lda,
    const unsigned short* __restrict__ Bt, int ldbt,
    TC* __restrict__ C, int ldc,
    int M, int K,
    const float* __restrict__ bias, int relu, int nwgx)
{
    constexpr int BM = 128, BK = 64;
    constexpr int WNW = (BN >= 128) ? 2 : 1;
    constexpr int WMW = 4 / WNW;
    constexpr int RW = BM / WMW;          // wave rows: 64 or 32
    constexpr int NI = RW / 16;           // 4 or 2
    constexpr int NJ = 4;                 // 64 cols per wave
    constexpr int NCHB = BN / 8;
    constexpr int PER_STAGE = 4 + NCHB / 4;
    __shared__ unsigned short Als[2][BM * BK];
    __shared__ unsigned short Bls[2][BN * BK];

    int swz = xcd_swz(blockIdx.x, gridDim.x);
    int bx = swz % nwgx, by = swz / nwgx;

    int tid = threadIdx.x;
    int lane = tid & 63, w = tid >> 6;
    int wm = (WNW == 2) ? (w >> 1) : w;
    int wn = (WNW == 2) ? (w & 1) : 0;
    int row0 = by * BM, col0 = bx * BN;

    int lr = lane >> 3;
    int scol = ((lane & 7) ^ lr) << 3;

    f32x4 acc[NI][NJ];
    #pragma unroll
    for (int i = 0; i < NI; i++)
        #pragma unroll
        for (int j = 0; j < NJ; j++) acc[i][j] = (f32x4){0.f, 0.f, 0.f, 0.f};

    auto stage = [&](int buf, int k0) {
        #pragma unroll
        for (int i = 0; i < 4; i++) {
            int ch = (w << 2) + i;
            gload_lds16(A + (size_t)(row0 + (ch << 3) + lr) * lda + k0 + scol,
                        &Als[buf][(ch << 9) + (lane << 3)]);
        }
        #pragma unroll
        for (int i = 0; i < NCHB / 4; i++) {
            int ch = w * (NCHB / 4) + i;
            gload_lds16(Bt + (size_t)(col0 + (ch << 3) + lr) * ldbt + k0 + scol,
                        &Bls[buf][(ch << 9) + (lane << 3)]);
        }
    };

    auto compute = [&](int buf) {
        #pragma unroll
        for (int kc = 0; kc < 2; kc++) {
            int ks = (kc << 2) + (lane >> 4);
            bf16x8 af[NI];
            #pragma unroll
            for (int i = 0; i < NI; i++) {
                int rr = wm * RW + (i << 4) + (lane & 15);
                af[i] = *(bf16x8*)&Als[buf][(rr << 6) + ((ks ^ (rr & 7)) << 3)];
            }
            bf16x8 bfr[NJ];
            #pragma unroll
            for (int j = 0; j < NJ; j++) {
                int rr = wn * 64 + (j << 4) + (lane & 15);
                bfr[j] = *(bf16x8*)&Bls[buf][(rr << 6) + ((ks ^ (rr & 7)) << 3)];
            }
            #pragma unroll
            for (int i = 0; i < NI; i++)
                #pragma unroll
                for (int j = 0; j < NJ; j++)
                    acc[i][j] = __builtin_amdgcn_mfma_f32_16x16x32_bf16(af[i], bfr[j], acc[i][j], 0, 0, 0);
        }
    };

    int NT = K >> 6;
    stage(0, 0);
    stage(1, BK);
    for (int t = 0; t < NT; ++t) {
        if (t < NT - 1)
            asm volatile("s_waitcnt vmcnt(%0)" :: "i"(PER_STAGE) : "memory");
        else
            asm volatile("s_waitcnt vmcnt(0)" ::: "memory");
        __builtin_amdgcn_s_barrier();
        compute(t & 1);
        if (t + 2 < NT) {
            __builtin_amdgcn_s_barrier();   // all waves done reading buf[t&1]
            stage(t & 1, (t + 2) << 6);
        }
    }

    #pragma unroll
    for (int i = 0; i < NI; i++) {
        #pragma unroll
        for (int rr = 0; rr < 4; rr++) {
            int row = row0 + wm * RW + (i << 4) + ((lane >> 4) << 2) + rr;
            if (row >= M) continue;
            #pragma unroll
            for (int j = 0; j < NJ; j++) {
                int col = col0 + wn * 64 + j * 16 + (lane & 15);
                float v = acc[i][j][rr] + (bias ? bias[col] : 0.f);
                if (relu) v = fmaxf(v, 0.f);
                storeC(C, (size_t)row * ldc + col, v);
            }
        }
    }
}

// ---------------- attention logits: wave per node, 4 ch/lane ----------------
__global__ __launch_bounds__(256) void logits_kernel(
    const unsigned short* __restrict__ hbuf,
    const float* __restrict__ a_src, const float* __restrict__ a_dst,
    float* __restrict__ al, float* __restrict__ ar)
{
    int w = threadIdx.x >> 6;
    int n = blockIdx.x * 4 + w;
    if (n >= NN) return;
    int lane = threadIdx.x & 63;
    int c4 = lane * 4;
    us4 hv = *(const us4*)&hbuf[(size_t)n * 256 + c4];
    fx4 asv = *(const fx4*)&a_src[c4];
    fx4 adv = *(const fx4*)&a_dst[c4];
    float ps = 0.f, pd = 0.f;
    #pragma unroll
    for (int k = 0; k < 4; k++) {
        float h = bf2f(hv[k]);
        ps += h * asv[k];
        pd += h * adv[k];
    }
    #pragma unroll
    for (int off = 8; off; off >>= 1) {
        ps += __shfl_xor(ps, off);
        pd += __shfl_xor(pd, off);
    }
    if ((lane & 15) == 0) {
        al[n * 4 + (lane >> 4)] = ps;
        ar[n * 4 + (lane >> 4)] = pd;
    }
}

// ---------------- GAT aggregation: wave per node, 4 ch/lane, unroll-4 ----------------
__global__ __launch_bounds__(256) void aggregate_kernel(
    const unsigned short* __restrict__ hbuf,
    const float* __restrict__ al, const float* __restrict__ ar,
    const int* __restrict__ indptr, const int* __restrict__ esrc,
    const float* __restrict__ bias,
    unsigned short* __restrict__ out, int ldo)
{
    int w = threadIdx.x >> 6;
    int n = blockIdx.x * 4 + w;
    if (n >= NN) return;
    int lane = threadIdx.x & 63;
    int myh = lane >> 4;
    int c4 = lane * 4;
    int beg = indptr[n], end = indptr[n + 1];

    fx4 arn = *(const fx4*)&ar[(size_t)n * 4];

    fx4 mv = (fx4){-1e30f, -1e30f, -1e30f, -1e30f};
    for (int j = beg + lane; j < end; j += 64) {
        fx4 a = *(const fx4*)&al[(size_t)esrc[j] * 4];
        #pragma unroll
        for (int h = 0; h < 4; h++) {
            float e = a[h] + arn[h];
            e = e > 0.f ? e : 0.2f * e;
            mv[h] = fmaxf(mv[h], e);
        }
    }
    #pragma unroll
    for (int off = 32; off; off >>= 1) {
        #pragma unroll
        for (int h = 0; h < 4; h++) mv[h] = fmaxf(mv[h], __shfl_xor(mv[h], off));
    }
    float m = mv[myh];
    float arh = arn[myh];

    float ssum = 0.f;
    fx4 acc = (fx4){0.f, 0.f, 0.f, 0.f};
    int j = beg;
    for (; j + 4 <= end; j += 4) {
        int s0 = esrc[j], s1 = esrc[j + 1], s2 = esrc[j + 2], s3 = esrc[j + 3];
        us4 h0 = *(const us4*)&hbuf[(size_t)s0 * 256 + c4];
        us4 h1 = *(const us4*)&hbuf[(size_t)s1 * 256 + c4];
        us4 h2 = *(const us4*)&hbuf[(size_t)s2 * 256 + c4];
        us4 h3 = *(const us4*)&hbuf[(size_t)s3 * 256 + c4];
        float a0 = al[(size_t)s0 * 4 + myh];
        float a1 = al[(size_t)s1 * 4 + myh];
        float a2 = al[(size_t)s2 * 4 + myh];
        float a3 = al[(size_t)s3 * 4 + myh];
        float e0 = a0 + arh; e0 = e0 > 0.f ? e0 : 0.2f * e0;
        float e1 = a1 + arh; e1 = e1 > 0.f ? e1 : 0.2f * e1;
        float e2 = a2 + arh; e2 = e2 > 0.f ? e2 : 0.2f * e2;
        float e3 = a3 + arh; e3 = e3 > 0.f ? e3 : 0.2f * e3;
        float x0 = __expf(e0 - m), x1 = __expf(e1 - m);
        float x2 = __expf(e2 - m), x3 = __expf(e3 - m);
        ssum += x0 + x1 + x2 + x3;
        #pragma unroll
        for (int k = 0; k < 4; k++)
            acc[k] += x0 * bf2f(h0[k]) + x1 * bf2f(h1[k])
                    + x2 * bf2f(h2[k]) + x3 * bf2f(h3[k]);
    }
    for (; j < end; j++) {
        int s = esrc[j];
        us4 hv = *(const us4*)&hbuf[(size_t)s * 256 + c4];
        float a = al[(size_t)s * 4 + myh];
        float e = a + arh; e = e > 0.f ? e : 0.2f * e;
        float ex = __expf(e - m);
        ssum += ex;
        #pragma unroll
        for (int k = 0; k < 4; k++) acc[k] += ex * bf2f(hv[k]);
    }

    float inv = 1.f / (ssum + 1e-16f);
    us4 o;
    #pragma unroll
    for (int k = 0; k < 4; k++) o[k] = f2bf(acc[k] * inv + bias[c4 + k]);
    *(us4*)&out[(size_t)n * ldo + c4] = o;
}

// ---------------- output gathers (vectorized) ----------------
__global__ void gather_feats(const float* __restrict__ Bf, const float* __restrict__ Tf,
                             const int* __restrict__ voc, const int* __restrict__ batch,
                             float* __restrict__ out)
{
    int i = blockIdx.x * blockDim.x + threadIdx.x;
    if (i < NN * 32) {
        int n = i >> 5, c4 = (i & 31) * 4;
        int t = voc[n];
        *(fx4*)&out[(size_t)n * 128 + c4] = *(const fx4*)&Bf[(size_t)t * 128 + c4];
        *(fx4*)&out[(size_t)NN * 128 + (size_t)n * 128 + c4] = *(const fx4*)&Tf[(size_t)t * 128 + c4];
    }
    if (i < NN) out[(size_t)NN * 128 * 2 + (size_t)NN * 64 + i] = (float)batch[i];
}

// ---------------- host-side orchestration ----------------
extern "C" void kernel_launch(void* const* d_in, const int* in_sizes, int n_in,
                              void* d_out, int out_size, void* d_ws, size_t ws_size,
                              hipStream_t stream) {
    const float* x     = (const float*)d_in[0];
    const int*   ei    = (const int*)d_in[1];
    const int*   batch = (const int*)d_in[2];
    const int*   voc   = (const int*)d_in[3];
    const float* Bf    = (const float*)d_in[4];
    const float* Tf    = (const float*)d_in[5];
    const float* W0    = (const float*)d_in[6];
    const float* as0   = (const float*)d_in[7];
    const float* ad0   = (const float*)d_in[8];
    const float* b0    = (const float*)d_in[9];
    const float* W1    = (const float*)d_in[10];
    const float* as1   = (const float*)d_in[11];
    const float* ad1   = (const float*)d_in[12];
    const float* b1    = (const float*)d_in[13];
    const float* W2    = (const float*)d_in[14];
    const float* as2   = (const float*)d_in[15];
    const float* ad2   = (const float*)d_in[16];
    const float* b2    = (const float*)d_in[17];
    const float* fcmax_w = (const float*)d_in[18];
    const float* fcmax_b = (const float*)d_in[19];
    const float* fc1_w = (const float*)d_in[20];
    const float* fc1_b = (const float*)d_in[21];
    const float* fc2_w = (const float*)d_in[22];
    const float* fc2_b = (const float*)d_in[23];
    const float* fc3_w = (const float*)d_in[24];
    const float* fc3_b = (const float*)d_in[25];
    float* out = (float*)d_out;

    char* p = (char*)d_ws;
    unsigned short* xb  = (unsigned short*)p; p += (size_t)NPAD * 128 * 2;
    unsigned short* hbuf= (unsigned short*)p; p += (size_t)NN * 256 * 2;
    unsigned short* z   = (unsigned short*)p; p += (size_t)NPAD * 1536 * 2;
    unsigned short* z1  = (unsigned short*)p; p += (size_t)NPAD * 512 * 2;
    unsigned short* h2  = (unsigned short*)p; p += (size_t)NPAD * 128 * 2;
    unsigned short* w0t = (unsigned short*)p; p += (size_t)128 * 256 * 2;
    unsigned short* w1t = (unsigned short*)p; p += (size_t)256 * 256 * 2;
    unsigned short* w2t = (unsigned short*)p; p += (size_t)256 * 256 * 2;
    unsigned short* wmt = (unsigned short*)p; p += (size_t)256 * 256 * 2;
    unsigned short* f1t = (unsigned short*)p; p += (size_t)1536 * 512 * 2;
    unsigned short* f2t = (unsigned short*)p; p += (size_t)512 * 128 * 2;
    unsigned short* f3t = (unsigned short*)p; p += (size_t)128 * 64 * 2;
    float* al   = (float*)p; p += (size_t)NN * 4 * 4;
    float* ar   = (float*)p; p += (size_t)NN * 4 * 4;
    int* cnt    = (int*)p;   p += (size_t)NN * 4;
    int* cursor = (int*)p;   p += (size_t)NN * 4;
    int* esrc   = (int*)p;   p += (size_t)ET * 4;
    int* indptr = (int*)p;   p += (size_t)(NN + 1) * 4;

    const int* e_src = ei;
    const int* e_dst = ei + EE;

    // ---- pre-pass: weights -> bf16 transposed, x -> bf16 ----
    transpose_bf16<<<dim3(4, 8),  256, 0, stream>>>(W0, w0t, 128, 256);
    transpose_bf16<<<dim3(8, 8),  256, 0, stream>>>(W1, w1t, 256, 256);
    transpose_bf16<<<dim3(8, 8),  256, 0, stream>>>(W2, w2t, 256, 256);
    transpose_bf16<<<dim3(8, 8),  256, 0, stream>>>(fcmax_w, wmt, 256, 256);
    transpose_bf16<<<dim3(48, 16),256, 0, stream>>>(fc1_w, f1t, 1536, 512);
    transpose_bf16<<<dim3(16, 4), 256, 0, stream>>>(fc2_w, f2t, 512, 128);
    transpose_bf16<<<dim3(4, 2),  256, 0, stream>>>(fc3_w, f3t, 128, 64);
    cvt_bf16_v4<<<(NN * 32 + 255) / 256, 256, 0, stream>>>(x, xb, NN * 32);

    // ---- CSR (dst-sorted incoming edges, incl. self-loops) ----
    count_init<<<(NN + 255) / 256, 256, 0, stream>>>(cnt);
    count_edges<<<(EE + 255) / 256, 256, 0, stream>>>(e_dst, cnt);
    scan_kernel<<<1, 1024, 0, stream>>>(cnt, indptr, cursor);
    scatter_self<<<(NN + 255) / 256, 256, 0, stream>>>(cursor, esrc);
    scatter_edges<<<(EE + 255) / 256, 256, 0, stream>>>(e_src, e_dst, cursor, esrc);

    // ---- independent output gathers ----
    gather_feats<<<(NN * 32 + 255) / 256, 256, 0, stream>>>(Bf, Tf, voc, batch, out);

    const int MB = NPAD / 128;   // 157
    const int SB = NPAD / 64;    // 314
    const int NB4 = (NN + 3) / 4;

    // ---- GAT layer 0 ----
    mfma_gemm<64, unsigned short><<<4 * MB, 256, 0, stream>>>(xb, 128, w0t, 128, hbuf, 256, NN, 128, nullptr, 0, 4);
    logits_kernel<<<NB4, 256, 0, stream>>>(hbuf, as0, ad0, al, ar);
    aggregate_kernel<<<NB4, 256, 0, stream>>>(hbuf, al, ar, indptr, esrc, b0, z + 0, 1536);
    mfma_gemm<64, unsigned short><<<4 * MB, 256, 0, stream>>>(z + 0, 1536, wmt, 256, z + 256, 1536, NN, 256, fcmax_b, 1, 4);

    // ---- GAT layer 1 ----
    mfma_gemm<64, unsigned short><<<4 * MB, 256, 0, stream>>>(z + 256, 1536, w1t, 256, hbuf, 256, NN, 256, nullptr, 0, 4);
    logits_kernel<<<NB4, 256, 0, stream>>>(hbuf, as1, ad1, al, ar);
    aggregate_kernel<<<NB4, 256, 0, stream>>>(hbuf, al, ar, indptr, esrc, b1, z + 512, 1536);
    mfma_gemm<64, unsigned short><<<4 * MB, 256, 0, stream>>>(z + 512, 1536, wmt, 256, z + 768, 1536, NN, 256, fcmax_b, 1, 4);

    // ---- GAT layer 2 ----
    mfma_gemm<64, unsigned short><<<4 * MB, 256, 0, stream>>>(z + 768, 1536, w2t, 256, hbuf, 256, NN, 256, nullptr, 0, 4);
    logits_kernel<<<NB4, 256, 0, stream>>>(hbuf, as2, ad2, al, ar);
    aggregate_kernel<<<NB4, 256, 0, stream>>>(hbuf, al, ar, indptr, esrc, b2, z + 1024, 1536);
    mfma_gemm<64, unsigned short><<<4 * MB, 256, 0, stream>>>(z + 1024, 1536, wmt, 256, z + 1280, 1536, NN, 256, fcmax_b, 1, 4);

    // ---- MLP head ----
    mfma_gemm<128, unsigned short><<<4 * MB, 256, 0, stream>>>(z, 1536, f1t, 1536, z1, 512, NN, 1536, fc1_b, 1, 4);
    mfma_gemm<64, unsigned short><<<2 * MB, 256, 0, stream>>>(z1, 512, f2t, 512, h2, 128, NN, 512, fc2_b, 1, 2);
    sshot_gemm<128, float><<<1 * SB, 256, 0, stream>>>(h2, 128, f3t, 128, out + (size_t)2 * NN * 128, 64, NN, fc3_b, 0, 1);
}

// Round 10
// 328.726 us; speedup vs baseline: 1.1484x; 1.0978x over previous
//
#include <hip/hip_runtime.h>
#include <math.h>

#define NN 20000
#define NPAD 20096   // 157*128 = 314*64: staging reads never go OOB
#define EE 320000
#define ET (EE + NN)

typedef __attribute__((ext_vector_type(8))) short bf16x8;
typedef __attribute__((ext_vector_type(4))) float f32x4;
typedef __attribute__((ext_vector_type(4))) unsigned short us4;
typedef __attribute__((ext_vector_type(8))) unsigned short us8;
typedef __attribute__((ext_vector_type(4))) float fx4;

__device__ inline unsigned short f2bf(float f) {
    union { float f; unsigned u; } x; x.f = f;
    unsigned u = x.u;
    return (unsigned short)((u + 0x7FFF + ((u >> 16) & 1)) >> 16);
}
__device__ inline float bf2f(unsigned short u) {
    union { unsigned u; float f; } x; x.u = (unsigned)u << 16; return x.f;
}

__device__ inline void storeC(float* C, size_t idx, float v) { C[idx] = v; }
__device__ inline void storeC(unsigned short* C, size_t idx, float v) { C[idx] = f2bf(v); }

// async 16B/lane global -> LDS (linear dest: wave base + lane*16)
__device__ inline void gload_lds16(const void* g, void* l) {
    __builtin_amdgcn_global_load_lds(
        (const __attribute__((address_space(1))) unsigned int*)g,
        (__attribute__((address_space(3))) unsigned int*)l, 16, 0, 0);
}

// bijective XCD-chunked swizzle (m204)
__device__ inline int xcd_swz(int orig, int nwg) {
    int q = nwg >> 3, r = nwg & 7;
    int xcd = orig & 7, loc = orig >> 3;
    return (xcd < r ? xcd * (q + 1) : r * (q + 1) + (xcd - r) * q) + loc;
}

// ---------------- pre-pass: weight transpose+convert, x convert ----------------
__global__ __launch_bounds__(256) void transpose_bf16(const float* __restrict__ W,
                                                      unsigned short* __restrict__ Wt,
                                                      int K, int N) {
    __shared__ float t[32][33];
    int k0 = blockIdx.x * 32, n0 = blockIdx.y * 32;
    int c = threadIdx.x & 31, r8 = threadIdx.x >> 5;
    #pragma unroll
    for (int i = 0; i < 4; i++)
        t[r8 + i * 8][c] = W[(size_t)(k0 + r8 + i * 8) * N + n0 + c];
    __syncthreads();
    #pragma unroll
    for (int i = 0; i < 4; i++)
        Wt[(size_t)(n0 + r8 + i * 8) * K + k0 + c] = f2bf(t[c][r8 + i * 8]);
}

__global__ void cvt_bf16_v4(const float* __restrict__ in, unsigned short* __restrict__ out, int n4) {
    int i = blockIdx.x * blockDim.x + threadIdx.x;
    if (i < n4) {
        fx4 v = *(const fx4*)(in + (size_t)i * 4);
        us4 s;
        #pragma unroll
        for (int j = 0; j < 4; j++) s[j] = f2bf(v[j]);
        *(us4*)(out + (size_t)i * 4) = s;
    }
}

// ---------------- CSR construction ----------------
__global__ void count_init(int* cnt) {
    int n = blockIdx.x * blockDim.x + threadIdx.x;
    if (n < NN) cnt[n] = 1;  // self-loop
}

__global__ void count_edges(const int* dst, int* cnt) {
    int e = blockIdx.x * blockDim.x + threadIdx.x;
    if (e < EE) atomicAdd(&cnt[dst[e]], 1);
}

__global__ void scan_kernel(const int* cnt, int* indptr, int* cursor) {
    __shared__ int part[1024];
    int tid = threadIdx.x;
    const int CH = 20;
    int base = tid * CH;
    int sum = 0;
    for (int i = 0; i < CH; i++) {
        int idx = base + i;
        if (idx < NN) sum += cnt[idx];
    }
    part[tid] = sum;
    __syncthreads();
    for (int off = 1; off < 1024; off <<= 1) {
        int v = (tid >= off) ? part[tid - off] : 0;
        __syncthreads();
        part[tid] += v;
        __syncthreads();
    }
    int run = (tid == 0) ? 0 : part[tid - 1];
    for (int i = 0; i < CH; i++) {
        int idx = base + i;
        if (idx < NN) {
            indptr[idx] = run;
            cursor[idx] = run;
            run += cnt[idx];
        }
    }
    if (tid == 1023) indptr[NN] = run;
}

__global__ void scatter_self(int* cursor, int* esrc) {
    int n = blockIdx.x * blockDim.x + threadIdx.x;
    if (n < NN) {
        int pos = atomicAdd(&cursor[n], 1);
        esrc[pos] = n;
    }
}

__global__ void scatter_edges(const int* src, const int* dst, int* cursor, int* esrc) {
    int e = blockIdx.x * blockDim.x + threadIdx.x;
    if (e < EE) {
        int pos = atomicAdd(&cursor[dst[e]], 1);
        esrc[pos] = src[e];
    }
}

// ---------------- single-shot GEMM (fc3 only: N=64, K=128) ----------------
template <int KTOT, typename TC>
__global__ __launch_bounds__(256) void sshot_gemm(
    const unsigned short* __restrict__ A, int lda,
    const unsigned short* __restrict__ Bt, int ldbt,
    TC* __restrict__ C, int ldc,
    int M, const float* __restrict__ bias, int relu, int nwgx)
{
    constexpr int LPR = KTOT / 8;
    constexpr int RPC = 512 / KTOT;
    constexpr int NCH = KTOT / 8;
    constexpr int NCHW = NCH / 4;
    constexpr int KC = KTOT / 32;
    __shared__ unsigned short Als[64 * KTOT];
    __shared__ unsigned short Bls[64 * KTOT];

    int swz = xcd_swz(blockIdx.x, gridDim.x);
    int bx = swz % nwgx, by = swz / nwgx;
    int row0 = by * 64, col0 = bx * 64;

    int tid = threadIdx.x;
    int lane = tid & 63, w = tid >> 6;
    int ric = lane / LPR, slot = lane % LPR;

    #pragma unroll
    for (int i = 0; i < NCHW; i++) {
        int ch = w * NCHW + i;
        int r = ch * RPC + ric;
        gload_lds16(A + (size_t)(row0 + r) * lda + ((slot ^ (r & 7)) << 3),
                    &Als[ch * 512 + lane * 8]);
    }
    #pragma unroll
    for (int i = 0; i < NCHW; i++) {
        int ch = w * NCHW + i;
        int r = ch * RPC + ric;
        gload_lds16(Bt + (size_t)(col0 + r) * ldbt + ((slot ^ (r & 7)) << 3),
                    &Bls[ch * 512 + lane * 8]);
    }
    __syncthreads();

    f32x4 acc[4];
    #pragma unroll
    for (int j = 0; j < 4; j++) acc[j] = (f32x4){0.f, 0.f, 0.f, 0.f};

    #pragma unroll
    for (int kc = 0; kc < KC; kc++) {
        int ks = (kc << 2) + (lane >> 4);
        int ra = (w << 4) + (lane & 15);
        bf16x8 af = *(bf16x8*)&Als[ra * KTOT + ((ks ^ (ra & 7)) << 3)];
        #pragma unroll
        for (int j = 0; j < 4; j++) {
            int rb = (j << 4) + (lane & 15);
            bf16x8 bf = *(bf16x8*)&Bls[rb * KTOT + ((ks ^ (rb & 7)) << 3)];
            acc[j] = __builtin_amdgcn_mfma_f32_16x16x32_bf16(af, bf, acc[j], 0, 0, 0);
        }
    }

    #pragma unroll
    for (int rr = 0; rr < 4; rr++) {
        int row = row0 + (w << 4) + ((lane >> 4) << 2) + rr;
        if (row >= M) continue;
        #pragma unroll
        for (int j = 0; j < 4; j++) {
            int col = col0 + j * 16 + (lane & 15);
            float v = acc[j][rr] + (bias ? bias[col] : 0.f);
            if (relu) v = fmaxf(v, 0.f);
            storeC(C, (size_t)row * ldc + col, v);
        }
    }
}

// ---------------- pipelined GEMM: depth-2 counted vmcnt; optional fused logits ----------------
// BN=64 only when LOGITS=true (block covers one head's 64 cols).
template <int BN, typename TC, bool LOGITS>
__global__ __launch_bounds__(256) void mfma_gemm(
    const unsigned short* __restrict__ A, int lda,
    const unsigned short* __restrict__ Bt, int ldbt,
    TC* __restrict__ C, int ldc,
    int M, int K,
    const float* __restrict__ bias, int relu, int nwgx,
    const float* __restrict__ asrc, const float* __restrict__ adst,
    float* __restrict__ al, float* __restrict__ ar)
{
    constexpr int BM = 128, BK = 64;
    constexpr int WNW = (BN >= 128) ? 2 : 1;
    constexpr int WMW = 4 / WNW;
    constexpr int RW = BM / WMW;          // wave rows: 64 or 32
    constexpr int NI = RW / 16;           // 4 or 2
    constexpr int NJ = 4;                 // 64 cols per wave
    constexpr int NCHB = BN / 8;
    constexpr int PER_STAGE = 4 + NCHB / 4;
    __shared__ unsigned short Als[2][BM * BK];
    __shared__ unsigned short Bls[2][BN * BK];

    int swz = xcd_swz(blockIdx.x, gridDim.x);
    int bx = swz % nwgx, by = swz / nwgx;

    int tid = threadIdx.x;
    int lane = tid & 63, w = tid >> 6;
    int wm = (WNW == 2) ? (w >> 1) : w;
    int wn = (WNW == 2) ? (w & 1) : 0;
    int row0 = by * BM, col0 = bx * BN;

    int lr = lane >> 3;
    int scol = ((lane & 7) ^ lr) << 3;

    f32x4 acc[NI][NJ];
    #pragma unroll
    for (int i = 0; i < NI; i++)
        #pragma unroll
        for (int j = 0; j < NJ; j++) acc[i][j] = (f32x4){0.f, 0.f, 0.f, 0.f};

    auto stage = [&](int buf, int k0) {
        #pragma unroll
        for (int i = 0; i < 4; i++) {
            int ch = (w << 2) + i;
            gload_lds16(A + (size_t)(row0 + (ch << 3) + lr) * lda + k0 + scol,
                        &Als[buf][(ch << 9) + (lane << 3)]);
        }
        #pragma unroll
        for (int i = 0; i < NCHB / 4; i++) {
            int ch = w * (NCHB / 4) + i;
            gload_lds16(Bt + (size_t)(col0 + (ch << 3) + lr) * ldbt + k0 + scol,
                        &Bls[buf][(ch << 9) + (lane << 3)]);
        }
    };

    auto compute = [&](int buf) {
        #pragma unroll
        for (int kc = 0; kc < 2; kc++) {
            int ks = (kc << 2) + (lane >> 4);
            bf16x8 af[NI];
            #pragma unroll
            for (int i = 0; i < NI; i++) {
                int rr = wm * RW + (i << 4) + (lane & 15);
                af[i] = *(bf16x8*)&Als[buf][(rr << 6) + ((ks ^ (rr & 7)) << 3)];
            }
            bf16x8 bfr[NJ];
            #pragma unroll
            for (int j = 0; j < NJ; j++) {
                int rr = wn * 64 + (j << 4) + (lane & 15);
                bfr[j] = *(bf16x8*)&Bls[buf][(rr << 6) + ((ks ^ (rr & 7)) << 3)];
            }
            #pragma unroll
            for (int i = 0; i < NI; i++)
                #pragma unroll
                for (int j = 0; j < NJ; j++)
                    acc[i][j] = __builtin_amdgcn_mfma_f32_16x16x32_bf16(af[i], bfr[j], acc[i][j], 0, 0, 0);
        }
    };

    int NT = K >> 6;
    stage(0, 0);
    stage(1, BK);
    for (int t = 0; t < NT; ++t) {
        if (t < NT - 1)
            asm volatile("s_waitcnt vmcnt(%0)" :: "i"(PER_STAGE) : "memory");
        else
            asm volatile("s_waitcnt vmcnt(0)" ::: "memory");
        __builtin_amdgcn_s_barrier();
        compute(t & 1);
        if (t + 2 < NT) {
            __builtin_amdgcn_s_barrier();   // all waves done reading buf[t&1]
            stage(t & 1, (t + 2) << 6);
        }
    }

    if constexpr (LOGITS) {
        // block covers head hh = col0/64; epilogue computes al/ar rows directly
        int hh = col0 >> 6;
        float as_j[NJ], ad_j[NJ];
        #pragma unroll
        for (int j = 0; j < NJ; j++) {
            int cl = j * 16 + (lane & 15);
            as_j[j] = asrc[hh * 64 + cl];
            ad_j[j] = adst[hh * 64 + cl];
        }
        #pragma unroll
        for (int i = 0; i < NI; i++) {
            #pragma unroll
            for (int rr = 0; rr < 4; rr++) {
                int row = row0 + wm * RW + (i << 4) + ((lane >> 4) << 2) + rr;
                float ps = 0.f, pd = 0.f;
                #pragma unroll
                for (int j = 0; j < NJ; j++) {
                    float v = acc[i][j][rr];
                    ps += v * as_j[j];
                    pd += v * ad_j[j];
                    if (row < M) {
                        int col = col0 + j * 16 + (lane & 15);
                        storeC(C, (size_t)row * ldc + col, v);
                    }
                }
                #pragma unroll
                for (int off = 8; off; off >>= 1) {
                    ps += __shfl_xor(ps, off);
                    pd += __shfl_xor(pd, off);
                }
                if ((lane & 15) == 0 && row < M) {
                    al[row * 4 + hh] = ps;
                    ar[row * 4 + hh] = pd;
                }
            }
        }
    } else {
        #pragma unroll
        for (int i = 0; i < NI; i++) {
            #pragma unroll
            for (int rr = 0; rr < 4; rr++) {
                int row = row0 + wm * RW + (i << 4) + ((lane >> 4) << 2) + rr;
                if (row >= M) continue;
                #pragma unroll
                for (int j = 0; j < NJ; j++) {
                    int col = col0 + wn * 64 + j * 16 + (lane & 15);
                    float v = acc[i][j][rr] + (bias ? bias[col] : 0.f);
                    if (relu) v = fmaxf(v, 0.f);
                    storeC(C, (size_t)row * ldc + col, v);
                }
            }
        }
    }
}

// ---------------- GAT aggregation: wave per node, 4 ch/lane, unroll-4 ----------------
__global__ __launch_bounds__(256) void aggregate_kernel(
    const unsigned short* __restrict__ hbuf,
    const float* __restrict__ al, const float* __restrict__ ar,
    const int* __restrict__ indptr, const int* __restrict__ esrc,
    const float* __restrict__ bias,
    unsigned short* __restrict__ out, int ldo)
{
    int w = threadIdx.x >> 6;
    int n = blockIdx.x * 4 + w;
    if (n >= NN) return;
    int lane = threadIdx.x & 63;
    int myh = lane >> 4;
    int c4 = lane * 4;
    int beg = indptr[n], end = indptr[n + 1];

    fx4 arn = *(const fx4*)&ar[(size_t)n * 4];

    fx4 mv = (fx4){-1e30f, -1e30f, -1e30f, -1e30f};
    for (int j = beg + lane; j < end; j += 64) {
        fx4 a = *(const fx4*)&al[(size_t)esrc[j] * 4];
        #pragma unroll
        for (int h = 0; h < 4; h++) {
            float e = a[h] + arn[h];
            e = e > 0.f ? e : 0.2f * e;
            mv[h] = fmaxf(mv[h], e);
        }
    }
    #pragma unroll
    for (int off = 32; off; off >>= 1) {
        #pragma unroll
        for (int h = 0; h < 4; h++) mv[h] = fmaxf(mv[h], __shfl_xor(mv[h], off));
    }
    float m = mv[myh];
    float arh = arn[myh];

    float ssum = 0.f;
    fx4 acc = (fx4){0.f, 0.f, 0.f, 0.f};
    int j = beg;
    for (; j + 4 <= end; j += 4) {
        int s0 = esrc[j], s1 = esrc[j + 1], s2 = esrc[j + 2], s3 = esrc[j + 3];
        us4 h0 = *(const us4*)&hbuf[(size_t)s0 * 256 + c4];
        us4 h1 = *(const us4*)&hbuf[(size_t)s1 * 256 + c4];
        us4 h2 = *(const us4*)&hbuf[(size_t)s2 * 256 + c4];
        us4 h3 = *(const us4*)&hbuf[(size_t)s3 * 256 + c4];
        float a0 = al[(size_t)s0 * 4 + myh];
        float a1 = al[(size_t)s1 * 4 + myh];
        float a2 = al[(size_t)s2 * 4 + myh];
        float a3 = al[(size_t)s3 * 4 + myh];
        float e0 = a0 + arh; e0 = e0 > 0.f ? e0 : 0.2f * e0;
        float e1 = a1 + arh; e1 = e1 > 0.f ? e1 : 0.2f * e1;
        float e2 = a2 + arh; e2 = e2 > 0.f ? e2 : 0.2f * e2;
        float e3 = a3 + arh; e3 = e3 > 0.f ? e3 : 0.2f * e3;
        float x0 = __expf(e0 - m), x1 = __expf(e1 - m);
        float x2 = __expf(e2 - m), x3 = __expf(e3 - m);
        ssum += x0 + x1 + x2 + x3;
        #pragma unroll
        for (int k = 0; k < 4; k++)
            acc[k] += x0 * bf2f(h0[k]) + x1 * bf2f(h1[k])
                    + x2 * bf2f(h2[k]) + x3 * bf2f(h3[k]);
    }
    for (; j < end; j++) {
        int s = esrc[j];
        us4 hv = *(const us4*)&hbuf[(size_t)s * 256 + c4];
        float a = al[(size_t)s * 4 + myh];
        float e = a + arh; e = e > 0.f ? e : 0.2f * e;
        float ex = __expf(e - m);
        ssum += ex;
        #pragma unroll
        for (int k = 0; k < 4; k++) acc[k] += ex * bf2f(hv[k]);
    }

    float inv = 1.f / (ssum + 1e-16f);
    us4 o;
    #pragma unroll
    for (int k = 0; k < 4; k++) o[k] = f2bf(acc[k] * inv + bias[c4 + k]);
    *(us4*)&out[(size_t)n * ldo + c4] = o;
}

// ---------------- output gathers (vectorized) ----------------
__global__ void gather_feats(const float* __restrict__ Bf, const float* __restrict__ Tf,
                             const int* __restrict__ voc, const int* __restrict__ batch,
                             float* __restrict__ out)
{
    int i = blockIdx.x * blockDim.x + threadIdx.x;
    if (i < NN * 32) {
        int n = i >> 5, c4 = (i & 31) * 4;
        int t = voc[n];
        *(fx4*)&out[(size_t)n * 128 + c4] = *(const fx4*)&Bf[(size_t)t * 128 + c4];
        *(fx4*)&out[(size_t)NN * 128 + (size_t)n * 128 + c4] = *(const fx4*)&Tf[(size_t)t * 128 + c4];
    }
    if (i < NN) out[(size_t)NN * 128 * 2 + (size_t)NN * 64 + i] = (float)batch[i];
}

// ---------------- host-side orchestration ----------------
extern "C" void kernel_launch(void* const* d_in, const int* in_sizes, int n_in,
                              void* d_out, int out_size, void* d_ws, size_t ws_size,
                              hipStream_t stream) {
    const float* x     = (const float*)d_in[0];
    const int*   ei    = (const int*)d_in[1];
    const int*   batch = (const int*)d_in[2];
    const int*   voc   = (const int*)d_in[3];
    const float* Bf    = (const float*)d_in[4];
    const float* Tf    = (const float*)d_in[5];
    const float* W0    = (const float*)d_in[6];
    const float* as0   = (const float*)d_in[7];
    const float* ad0   = (const float*)d_in[8];
    const float* b0    = (const float*)d_in[9];
    const float* W1    = (const float*)d_in[10];
    const float* as1   = (const float*)d_in[11];
    const float* ad1   = (const float*)d_in[12];
    const float* b1    = (const float*)d_in[13];
    const float* W2    = (const float*)d_in[14];
    const float* as2   = (const float*)d_in[15];
    const float* ad2   = (const float*)d_in[16];
    const float* b2    = (const float*)d_in[17];
    const float* fcmax_w = (const float*)d_in[18];
    const float* fcmax_b = (const float*)d_in[19];
    const float* fc1_w = (const float*)d_in[20];
    const float* fc1_b = (const float*)d_in[21];
    const float* fc2_w = (const float*)d_in[22];
    const float* fc2_b = (const float*)d_in[23];
    const float* fc3_w = (const float*)d_in[24];
    const float* fc3_b = (const float*)d_in[25];
    float* out = (float*)d_out;

    char* p = (char*)d_ws;
    unsigned short* xb  = (unsigned short*)p; p += (size_t)NPAD * 128 * 2;
    unsigned short* hbuf= (unsigned short*)p; p += (size_t)NN * 256 * 2;
    unsigned short* z   = (unsigned short*)p; p += (size_t)NPAD * 1536 * 2;
    unsigned short* z1  = (unsigned short*)p; p += (size_t)NPAD * 512 * 2;
    unsigned short* h2  = (unsigned short*)p; p += (size_t)NPAD * 128 * 2;
    unsigned short* w0t = (unsigned short*)p; p += (size_t)128 * 256 * 2;
    unsigned short* w1t = (unsigned short*)p; p += (size_t)256 * 256 * 2;
    unsigned short* w2t = (unsigned short*)p; p += (size_t)256 * 256 * 2;
    unsigned short* wmt = (unsigned short*)p; p += (size_t)256 * 256 * 2;
    unsigned short* f1t = (unsigned short*)p; p += (size_t)1536 * 512 * 2;
    unsigned short* f2t = (unsigned short*)p; p += (size_t)512 * 128 * 2;
    unsigned short* f3t = (unsigned short*)p; p += (size_t)128 * 64 * 2;
    float* al   = (float*)p; p += (size_t)NN * 4 * 4;
    float* ar   = (float*)p; p += (size_t)NN * 4 * 4;
    int* cnt    = (int*)p;   p += (size_t)NN * 4;
    int* cursor = (int*)p;   p += (size_t)NN * 4;
    int* esrc   = (int*)p;   p += (size_t)ET * 4;
    int* indptr = (int*)p;   p += (size_t)(NN + 1) * 4;

    const int* e_src = ei;
    const int* e_dst = ei + EE;

    // ---- pre-pass: weights -> bf16 transposed, x -> bf16 ----
    transpose_bf16<<<dim3(4, 8),  256, 0, stream>>>(W0, w0t, 128, 256);
    transpose_bf16<<<dim3(8, 8),  256, 0, stream>>>(W1, w1t, 256, 256);
    transpose_bf16<<<dim3(8, 8),  256, 0, stream>>>(W2, w2t, 256, 256);
    transpose_bf16<<<dim3(8, 8),  256, 0, stream>>>(fcmax_w, wmt, 256, 256);
    transpose_bf16<<<dim3(48, 16),256, 0, stream>>>(fc1_w, f1t, 1536, 512);
    transpose_bf16<<<dim3(16, 4), 256, 0, stream>>>(fc2_w, f2t, 512, 128);
    transpose_bf16<<<dim3(4, 2),  256, 0, stream>>>(fc3_w, f3t, 128, 64);
    cvt_bf16_v4<<<(NN * 32 + 255) / 256, 256, 0, stream>>>(x, xb, NN * 32);

    // ---- CSR (dst-sorted incoming edges, incl. self-loops) ----
    count_init<<<(NN + 255) / 256, 256, 0, stream>>>(cnt);
    count_edges<<<(EE + 255) / 256, 256, 0, stream>>>(e_dst, cnt);
    scan_kernel<<<1, 1024, 0, stream>>>(cnt, indptr, cursor);
    scatter_self<<<(NN + 255) / 256, 256, 0, stream>>>(cursor, esrc);
    scatter_edges<<<(EE + 255) / 256, 256, 0, stream>>>(e_src, e_dst, cursor, esrc);

    // ---- independent output gathers ----
    gather_feats<<<(NN * 32 + 255) / 256, 256, 0, stream>>>(Bf, Tf, voc, batch, out);

    const int MB = NPAD / 128;   // 157
    const int SB = NPAD / 64;    // 314
    const int NB4 = (NN + 3) / 4;

    // ---- GAT layer 0 (h-GEMM with fused logits) ----
    mfma_gemm<64, unsigned short, true><<<4 * MB, 256, 0, stream>>>(xb, 128, w0t, 128, hbuf, 256, NN, 128, nullptr, 0, 4, as0, ad0, al, ar);
    aggregate_kernel<<<NB4, 256, 0, stream>>>(hbuf, al, ar, indptr, esrc, b0, z + 0, 1536);
    mfma_gemm<64, unsigned short, false><<<4 * MB, 256, 0, stream>>>(z + 0, 1536, wmt, 256, z + 256, 1536, NN, 256, fcmax_b, 1, 4, nullptr, nullptr, nullptr, nullptr);

    // ---- GAT layer 1 ----
    mfma_gemm<64, unsigned short, true><<<4 * MB, 256, 0, stream>>>(z + 256, 1536, w1t, 256, hbuf, 256, NN, 256, nullptr, 0, 4, as1, ad1, al, ar);
    aggregate_kernel<<<NB4, 256, 0, stream>>>(hbuf, al, ar, indptr, esrc, b1, z + 512, 1536);
    mfma_gemm<64, unsigned short, false><<<4 * MB, 256, 0, stream>>>(z + 512, 1536, wmt, 256, z + 768, 1536, NN, 256, fcmax_b, 1, 4, nullptr, nullptr, nullptr, nullptr);

    // ---- GAT layer 2 ----
    mfma_gemm<64, unsigned short, true><<<4 * MB, 256, 0, stream>>>(z + 768, 1536, w2t, 256, hbuf, 256, NN, 256, nullptr, 0, 4, as2, ad2, al, ar);
    aggregate_kernel<<<NB4, 256, 0, stream>>>(hbuf, al, ar, indptr, esrc, b2, z + 1024, 1536);
    mfma_gemm<64, unsigned short, false><<<4 * MB, 256, 0, stream>>>(z + 1024, 1536, wmt, 256, z + 1280, 1536, NN, 256, fcmax_b, 1, 4, nullptr, nullptr, nullptr, nullptr);

    // ---- MLP head ----
    mfma_gemm<64, unsigned short, false><<<8 * MB, 256, 0, stream>>>(z, 1536, f1t, 1536, z1, 512, NN, 1536, fc1_b, 1, 8, nullptr, nullptr, nullptr, nullptr);
    mfma_gemm<64, unsigned short, false><<<2 * MB, 256, 0, stream>>>(z1, 512, f2t, 512, h2, 128, NN, 512, fc2_b, 1, 2, nullptr, nullptr, nullptr, nullptr);
    sshot_gemm<128, float><<<1 * SB, 256, 0, stream>>>(h2, 128, f3t, 128, out + (size_t)2 * NN * 128, 64, NN, fc3_b, 0, 1);
}

// Round 11
// 320.263 us; speedup vs baseline: 1.1787x; 1.0264x over previous
//
#include <hip/hip_runtime.h>
#include <math.h>

#define NN 20000
#define NPAD 20096   // 157*128 = 314*64: staging reads never go OOB
#define EE 320000
#define ET (EE + NN)

typedef __attribute__((ext_vector_type(8))) short bf16x8;
typedef __attribute__((ext_vector_type(4))) float f32x4;
typedef __attribute__((ext_vector_type(4))) unsigned short us4;
typedef __attribute__((ext_vector_type(8))) unsigned short us8;
typedef __attribute__((ext_vector_type(4))) float fx4;

__device__ inline unsigned short f2bf(float f) {
    union { float f; unsigned u; } x; x.f = f;
    unsigned u = x.u;
    return (unsigned short)((u + 0x7FFF + ((u >> 16) & 1)) >> 16);
}
__device__ inline float bf2f(unsigned short u) {
    union { unsigned u; float f; } x; x.u = (unsigned)u << 16; return x.f;
}

__device__ inline void storeC(float* C, size_t idx, float v) { C[idx] = v; }
__device__ inline void storeC(unsigned short* C, size_t idx, float v) { C[idx] = f2bf(v); }

// async 16B/lane global -> LDS (linear dest: wave base + lane*16)
__device__ inline void gload_lds16(const void* g, void* l) {
    __builtin_amdgcn_global_load_lds(
        (const __attribute__((address_space(1))) unsigned int*)g,
        (__attribute__((address_space(3))) unsigned int*)l, 16, 0, 0);
}

// bijective XCD-chunked swizzle (m204)
__device__ inline int xcd_swz(int orig, int nwg) {
    int q = nwg >> 3, r = nwg & 7;
    int xcd = orig & 7, loc = orig >> 3;
    return (xcd < r ? xcd * (q + 1) : r * (q + 1) + (xcd - r) * q) + loc;
}

// ---------------- pre-pass: batched weight transpose+convert (1 launch) ----------------
__device__ inline void transpose_tile(const float* __restrict__ W, unsigned short* __restrict__ Wt,
                                      int K, int N, int lb) {
    __shared__ float t[32][33];
    int kb = K >> 5;
    int k0 = (lb % kb) * 32, n0 = (lb / kb) * 32;
    int c = threadIdx.x & 31, r8 = threadIdx.x >> 5;
    #pragma unroll
    for (int i = 0; i < 4; i++)
        t[r8 + i * 8][c] = W[(size_t)(k0 + r8 + i * 8) * N + n0 + c];
    __syncthreads();
    #pragma unroll
    for (int i = 0; i < 4; i++)
        Wt[(size_t)(n0 + r8 + i * 8) * K + k0 + c] = f2bf(t[c][r8 + i * 8]);
}

__global__ __launch_bounds__(256) void transpose_all(
    const float* s0, unsigned short* d0,   // 128x256  -> 32 blocks
    const float* s1, unsigned short* d1,   // 256x256  -> 64
    const float* s2, unsigned short* d2,   // 256x256  -> 64
    const float* s3, unsigned short* d3,   // 256x256  -> 64
    const float* s4, unsigned short* d4,   // 1536x512 -> 768
    const float* s5, unsigned short* d5,   // 512x128  -> 64
    const float* s6, unsigned short* d6)   // 128x64   -> 8
{
    int b = blockIdx.x;
    if      (b < 32)   transpose_tile(s0, d0, 128, 256, b);
    else if (b < 96)   transpose_tile(s1, d1, 256, 256, b - 32);
    else if (b < 160)  transpose_tile(s2, d2, 256, 256, b - 96);
    else if (b < 224)  transpose_tile(s3, d3, 256, 256, b - 160);
    else if (b < 992)  transpose_tile(s4, d4, 1536, 512, b - 224);
    else if (b < 1056) transpose_tile(s5, d5, 512, 128, b - 992);
    else               transpose_tile(s6, d6, 128, 64, b - 1056);
}

__global__ void cvt_bf16_v4(const float* __restrict__ in, unsigned short* __restrict__ out, int n4) {
    int i = blockIdx.x * blockDim.x + threadIdx.x;
    if (i < n4) {
        fx4 v = *(const fx4*)(in + (size_t)i * 4);
        us4 s;
        #pragma unroll
        for (int j = 0; j < 4; j++) s[j] = f2bf(v[j]);
        *(us4*)(out + (size_t)i * 4) = s;
    }
}

// ---------------- CSR construction ----------------
__global__ void count_edges(const int* dst, int* cnt) {
    int e = blockIdx.x * blockDim.x + threadIdx.x;
    if (e < EE) atomicAdd(&cnt[dst[e]], 1);
}

// scan folds the +1 self-loop per node and places it at slot 0 of each segment
__global__ void scan_kernel(const int* cnt, int* indptr, int* cursor, int* esrc) {
    __shared__ int part[1024];
    int tid = threadIdx.x;
    const int CH = 20;
    int base = tid * CH;
    int sum = 0;
    for (int i = 0; i < CH; i++) {
        int idx = base + i;
        if (idx < NN) sum += cnt[idx] + 1;
    }
    part[tid] = sum;
    __syncthreads();
    for (int off = 1; off < 1024; off <<= 1) {
        int v = (tid >= off) ? part[tid - off] : 0;
        __syncthreads();
        part[tid] += v;
        __syncthreads();
    }
    int run = (tid == 0) ? 0 : part[tid - 1];
    for (int i = 0; i < CH; i++) {
        int idx = base + i;
        if (idx < NN) {
            indptr[idx] = run;
            esrc[run] = idx;       // self-loop in slot 0
            cursor[idx] = run + 1;
            run += cnt[idx] + 1;
        }
    }
    if (tid == 1023) indptr[NN] = run;
}

__global__ void scatter_edges(const int* src, const int* dst, int* cursor, int* esrc) {
    int e = blockIdx.x * blockDim.x + threadIdx.x;
    if (e < EE) {
        int pos = atomicAdd(&cursor[dst[e]], 1);
        esrc[pos] = src[e];
    }
}

// ---------------- single-shot GEMM (fc3 only: N=64, K=128) ----------------
template <int KTOT, typename TC>
__global__ __launch_bounds__(256) void sshot_gemm(
    const unsigned short* __restrict__ A, int lda,
    const unsigned short* __restrict__ Bt, int ldbt,
    TC* __restrict__ C, int ldc,
    int M, const float* __restrict__ bias, int relu, int nwgx)
{
    constexpr int LPR = KTOT / 8;
    constexpr int RPC = 512 / KTOT;
    constexpr int NCH = KTOT / 8;
    constexpr int NCHW = NCH / 4;
    constexpr int KC = KTOT / 32;
    __shared__ unsigned short Als[64 * KTOT];
    __shared__ unsigned short Bls[64 * KTOT];

    int swz = xcd_swz(blockIdx.x, gridDim.x);
    int bx = swz % nwgx, by = swz / nwgx;
    int row0 = by * 64, col0 = bx * 64;

    int tid = threadIdx.x;
    int lane = tid & 63, w = tid >> 6;
    int ric = lane / LPR, slot = lane % LPR;

    #pragma unroll
    for (int i = 0; i < NCHW; i++) {
        int ch = w * NCHW + i;
        int r = ch * RPC + ric;
        gload_lds16(A + (size_t)(row0 + r) * lda + ((slot ^ (r & 7)) << 3),
                    &Als[ch * 512 + lane * 8]);
    }
    #pragma unroll
    for (int i = 0; i < NCHW; i++) {
        int ch = w * NCHW + i;
        int r = ch * RPC + ric;
        gload_lds16(Bt + (size_t)(col0 + r) * ldbt + ((slot ^ (r & 7)) << 3),
                    &Bls[ch * 512 + lane * 8]);
    }
    __syncthreads();

    f32x4 acc[4];
    #pragma unroll
    for (int j = 0; j < 4; j++) acc[j] = (f32x4){0.f, 0.f, 0.f, 0.f};

    #pragma unroll
    for (int kc = 0; kc < KC; kc++) {
        int ks = (kc << 2) + (lane >> 4);
        int ra = (w << 4) + (lane & 15);
        bf16x8 af = *(bf16x8*)&Als[ra * KTOT + ((ks ^ (ra & 7)) << 3)];
        #pragma unroll
        for (int j = 0; j < 4; j++) {
            int rb = (j << 4) + (lane & 15);
            bf16x8 bf = *(bf16x8*)&Bls[rb * KTOT + ((ks ^ (rb & 7)) << 3)];
            acc[j] = __builtin_amdgcn_mfma_f32_16x16x32_bf16(af, bf, acc[j], 0, 0, 0);
        }
    }

    #pragma unroll
    for (int rr = 0; rr < 4; rr++) {
        int row = row0 + (w << 4) + ((lane >> 4) << 2) + rr;
        if (row >= M) continue;
        #pragma unroll
        for (int j = 0; j < 4; j++) {
            int col = col0 + j * 16 + (lane & 15);
            float v = acc[j][rr] + (bias ? bias[col] : 0.f);
            if (relu) v = fmaxf(v, 0.f);
            storeC(C, (size_t)row * ldc + col, v);
        }
    }
}

// ---------------- pipelined GEMM: depth-2 counted vmcnt; optional fused logits ----------------
template <int BN, typename TC, bool LOGITS>
__global__ __launch_bounds__(256) void mfma_gemm(
    const unsigned short* __restrict__ A, int lda,
    const unsigned short* __restrict__ Bt, int ldbt,
    TC* __restrict__ C, int ldc,
    int M, int K,
    const float* __restrict__ bias, int relu, int nwgx,
    const float* __restrict__ asrc, const float* __restrict__ adst,
    float* __restrict__ al, float* __restrict__ ar)
{
    constexpr int BM = 128, BK = 64;
    constexpr int WNW = (BN >= 128) ? 2 : 1;
    constexpr int WMW = 4 / WNW;
    constexpr int RW = BM / WMW;
    constexpr int NI = RW / 16;
    constexpr int NJ = 4;
    constexpr int NCHB = BN / 8;
    constexpr int PER_STAGE = 4 + NCHB / 4;
    __shared__ unsigned short Als[2][BM * BK];
    __shared__ unsigned short Bls[2][BN * BK];

    int swz = xcd_swz(blockIdx.x, gridDim.x);
    int bx = swz % nwgx, by = swz / nwgx;

    int tid = threadIdx.x;
    int lane = tid & 63, w = tid >> 6;
    int wm = (WNW == 2) ? (w >> 1) : w;
    int wn = (WNW == 2) ? (w & 1) : 0;
    int row0 = by * BM, col0 = bx * BN;

    int lr = lane >> 3;
    int scol = ((lane & 7) ^ lr) << 3;

    f32x4 acc[NI][NJ];
    #pragma unroll
    for (int i = 0; i < NI; i++)
        #pragma unroll
        for (int j = 0; j < NJ; j++) acc[i][j] = (f32x4){0.f, 0.f, 0.f, 0.f};

    auto stage = [&](int buf, int k0) {
        #pragma unroll
        for (int i = 0; i < 4; i++) {
            int ch = (w << 2) + i;
            gload_lds16(A + (size_t)(row0 + (ch << 3) + lr) * lda + k0 + scol,
                        &Als[buf][(ch << 9) + (lane << 3)]);
        }
        #pragma unroll
        for (int i = 0; i < NCHB / 4; i++) {
            int ch = w * (NCHB / 4) + i;
            gload_lds16(Bt + (size_t)(col0 + (ch << 3) + lr) * ldbt + k0 + scol,
                        &Bls[buf][(ch << 9) + (lane << 3)]);
        }
    };

    auto compute = [&](int buf) {
        #pragma unroll
        for (int kc = 0; kc < 2; kc++) {
            int ks = (kc << 2) + (lane >> 4);
            bf16x8 af[NI];
            #pragma unroll
            for (int i = 0; i < NI; i++) {
                int rr = wm * RW + (i << 4) + (lane & 15);
                af[i] = *(bf16x8*)&Als[buf][(rr << 6) + ((ks ^ (rr & 7)) << 3)];
            }
            bf16x8 bfr[NJ];
            #pragma unroll
            for (int j = 0; j < NJ; j++) {
                int rr = wn * 64 + (j << 4) + (lane & 15);
                bfr[j] = *(bf16x8*)&Bls[buf][(rr << 6) + ((ks ^ (rr & 7)) << 3)];
            }
            #pragma unroll
            for (int i = 0; i < NI; i++)
                #pragma unroll
                for (int j = 0; j < NJ; j++)
                    acc[i][j] = __builtin_amdgcn_mfma_f32_16x16x32_bf16(af[i], bfr[j], acc[i][j], 0, 0, 0);
        }
    };

    int NT = K >> 6;
    stage(0, 0);
    stage(1, BK);
    for (int t = 0; t < NT; ++t) {
        if (t < NT - 1)
            asm volatile("s_waitcnt vmcnt(%0)" :: "i"(PER_STAGE) : "memory");
        else
            asm volatile("s_waitcnt vmcnt(0)" ::: "memory");
        __builtin_amdgcn_s_barrier();
        compute(t & 1);
        if (t + 2 < NT) {
            __builtin_amdgcn_s_barrier();
            stage(t & 1, (t + 2) << 6);
        }
    }

    if constexpr (LOGITS) {
        int hh = col0 >> 6;
        float as_j[NJ], ad_j[NJ];
        #pragma unroll
        for (int j = 0; j < NJ; j++) {
            int cl = j * 16 + (lane & 15);
            as_j[j] = asrc[hh * 64 + cl];
            ad_j[j] = adst[hh * 64 + cl];
        }
        #pragma unroll
        for (int i = 0; i < NI; i++) {
            #pragma unroll
            for (int rr = 0; rr < 4; rr++) {
                int row = row0 + wm * RW + (i << 4) + ((lane >> 4) << 2) + rr;
                float ps = 0.f, pd = 0.f;
                #pragma unroll
                for (int j = 0; j < NJ; j++) {
                    float v = acc[i][j][rr];
                    ps += v * as_j[j];
                    pd += v * ad_j[j];
                    if (row < M) {
                        int col = col0 + j * 16 + (lane & 15);
                        storeC(C, (size_t)row * ldc + col, v);
                    }
                }
                #pragma unroll
                for (int off = 8; off; off >>= 1) {
                    ps += __shfl_xor(ps, off);
                    pd += __shfl_xor(pd, off);
                }
                if ((lane & 15) == 0 && row < M) {
                    al[row * 4 + hh] = ps;
                    ar[row * 4 + hh] = pd;
                }
            }
        }
    } else {
        #pragma unroll
        for (int i = 0; i < NI; i++) {
            #pragma unroll
            for (int rr = 0; rr < 4; rr++) {
                int row = row0 + wm * RW + (i << 4) + ((lane >> 4) << 2) + rr;
                if (row >= M) continue;
                #pragma unroll
                for (int j = 0; j < NJ; j++) {
                    int col = col0 + wn * 64 + j * 16 + (lane & 15);
                    float v = acc[i][j][rr] + (bias ? bias[col] : 0.f);
                    if (relu) v = fmaxf(v, 0.f);
                    storeC(C, (size_t)row * ldc + col, v);
                }
            }
        }
    }
}

// ---------------- GAT aggregation: wave per node, 4 ch/lane, unroll-4, NO max pass ----------------
// alpha = exp(e-m)/sum exp(e-m) is independent of m; logits are O(1) here so exp(e) is safe.
__global__ __launch_bounds__(256) void aggregate_kernel(
    const unsigned short* __restrict__ hbuf,
    const float* __restrict__ al, const float* __restrict__ ar,
    const int* __restrict__ indptr, const int* __restrict__ esrc,
    const float* __restrict__ bias,
    unsigned short* __restrict__ out, int ldo)
{
    int w = threadIdx.x >> 6;
    int n = blockIdx.x * 4 + w;
    if (n >= NN) return;
    int lane = threadIdx.x & 63;
    int myh = lane >> 4;
    int c4 = lane * 4;
    int beg = indptr[n], end = indptr[n + 1];

    float arh = ar[(size_t)n * 4 + myh];

    float ssum = 0.f;
    fx4 acc = (fx4){0.f, 0.f, 0.f, 0.f};
    int j = beg;
    for (; j + 4 <= end; j += 4) {
        int s0 = esrc[j], s1 = esrc[j + 1], s2 = esrc[j + 2], s3 = esrc[j + 3];
        us4 h0 = *(const us4*)&hbuf[(size_t)s0 * 256 + c4];
        us4 h1 = *(const us4*)&hbuf[(size_t)s1 * 256 + c4];
        us4 h2 = *(const us4*)&hbuf[(size_t)s2 * 256 + c4];
        us4 h3 = *(const us4*)&hbuf[(size_t)s3 * 256 + c4];
        float a0 = al[(size_t)s0 * 4 + myh];
        float a1 = al[(size_t)s1 * 4 + myh];
        float a2 = al[(size_t)s2 * 4 + myh];
        float a3 = al[(size_t)s3 * 4 + myh];
        float e0 = a0 + arh; e0 = e0 > 0.f ? e0 : 0.2f * e0;
        float e1 = a1 + arh; e1 = e1 > 0.f ? e1 : 0.2f * e1;
        float e2 = a2 + arh; e2 = e2 > 0.f ? e2 : 0.2f * e2;
        float e3 = a3 + arh; e3 = e3 > 0.f ? e3 : 0.2f * e3;
        float x0 = __expf(e0), x1 = __expf(e1);
        float x2 = __expf(e2), x3 = __expf(e3);
        ssum += x0 + x1 + x2 + x3;
        #pragma unroll
        for (int k = 0; k < 4; k++)
            acc[k] += x0 * bf2f(h0[k]) + x1 * bf2f(h1[k])
                    + x2 * bf2f(h2[k]) + x3 * bf2f(h3[k]);
    }
    for (; j < end; j++) {
        int s = esrc[j];
        us4 hv = *(const us4*)&hbuf[(size_t)s * 256 + c4];
        float a = al[(size_t)s * 4 + myh];
        float e = a + arh; e = e > 0.f ? e : 0.2f * e;
        float ex = __expf(e);
        ssum += ex;
        #pragma unroll
        for (int k = 0; k < 4; k++) acc[k] += ex * bf2f(hv[k]);
    }

    float inv = 1.f / (ssum + 1e-16f);
    us4 o;
    #pragma unroll
    for (int k = 0; k < 4; k++) o[k] = f2bf(acc[k] * inv + bias[c4 + k]);
    *(us4*)&out[(size_t)n * ldo + c4] = o;
}

// ---------------- output gathers (vectorized) ----------------
__global__ void gather_feats(const float* __restrict__ Bf, const float* __restrict__ Tf,
                             const int* __restrict__ voc, const int* __restrict__ batch,
                             float* __restrict__ out)
{
    int i = blockIdx.x * blockDim.x + threadIdx.x;
    if (i < NN * 32) {
        int n = i >> 5, c4 = (i & 31) * 4;
        int t = voc[n];
        *(fx4*)&out[(size_t)n * 128 + c4] = *(const fx4*)&Bf[(size_t)t * 128 + c4];
        *(fx4*)&out[(size_t)NN * 128 + (size_t)n * 128 + c4] = *(const fx4*)&Tf[(size_t)t * 128 + c4];
    }
    if (i < NN) out[(size_t)NN * 128 * 2 + (size_t)NN * 64 + i] = (float)batch[i];
}

// ---------------- host-side orchestration ----------------
extern "C" void kernel_launch(void* const* d_in, const int* in_sizes, int n_in,
                              void* d_out, int out_size, void* d_ws, size_t ws_size,
                              hipStream_t stream) {
    const float* x     = (const float*)d_in[0];
    const int*   ei    = (const int*)d_in[1];
    const int*   batch = (const int*)d_in[2];
    const int*   voc   = (const int*)d_in[3];
    const float* Bf    = (const float*)d_in[4];
    const float* Tf    = (const float*)d_in[5];
    const float* W0    = (const float*)d_in[6];
    const float* as0   = (const float*)d_in[7];
    const float* ad0   = (const float*)d_in[8];
    const float* b0    = (const float*)d_in[9];
    const float* W1    = (const float*)d_in[10];
    const float* as1   = (const float*)d_in[11];
    const float* ad1   = (const float*)d_in[12];
    const float* b1    = (const float*)d_in[13];
    const float* W2    = (const float*)d_in[14];
    const float* as2   = (const float*)d_in[15];
    const float* ad2   = (const float*)d_in[16];
    const float* b2    = (const float*)d_in[17];
    const float* fcmax_w = (const float*)d_in[18];
    const float* fcmax_b = (const float*)d_in[19];
    const float* fc1_w = (const float*)d_in[20];
    const float* fc1_b = (const float*)d_in[21];
    const float* fc2_w = (const float*)d_in[22];
    const float* fc2_b = (const float*)d_in[23];
    const float* fc3_w = (const float*)d_in[24];
    const float* fc3_b = (const float*)d_in[25];
    float* out = (float*)d_out;

    char* p = (char*)d_ws;
    unsigned short* xb  = (unsigned short*)p; p += (size_t)NPAD * 128 * 2;
    unsigned short* hbuf= (unsigned short*)p; p += (size_t)NN * 256 * 2;
    unsigned short* z   = (unsigned short*)p; p += (size_t)NPAD * 1536 * 2;
    unsigned short* z1  = (unsigned short*)p; p += (size_t)NPAD * 512 * 2;
    unsigned short* h2  = (unsigned short*)p; p += (size_t)NPAD * 128 * 2;
    unsigned short* w0t = (unsigned short*)p; p += (size_t)128 * 256 * 2;
    unsigned short* w1t = (unsigned short*)p; p += (size_t)256 * 256 * 2;
    unsigned short* w2t = (unsigned short*)p; p += (size_t)256 * 256 * 2;
    unsigned short* wmt = (unsigned short*)p; p += (size_t)256 * 256 * 2;
    unsigned short* f1t = (unsigned short*)p; p += (size_t)1536 * 512 * 2;
    unsigned short* f2t = (unsigned short*)p; p += (size_t)512 * 128 * 2;
    unsigned short* f3t = (unsigned short*)p; p += (size_t)128 * 64 * 2;
    float* al   = (float*)p; p += (size_t)NN * 4 * 4;
    float* ar   = (float*)p; p += (size_t)NN * 4 * 4;
    int* cnt    = (int*)p;   p += (size_t)NN * 4;
    int* cursor = (int*)p;   p += (size_t)NN * 4;
    int* esrc   = (int*)p;   p += (size_t)ET * 4;
    int* indptr = (int*)p;   p += (size_t)(NN + 1) * 4;

    const int* e_src = ei;
    const int* e_dst = ei + EE;

    // ---- pre-pass: weights -> bf16 transposed (1 launch), x -> bf16 ----
    transpose_all<<<1064, 256, 0, stream>>>(W0, w0t, W1, w1t, W2, w2t, fcmax_w, wmt,
                                            fc1_w, f1t, fc2_w, f2t, fc3_w, f3t);
    cvt_bf16_v4<<<(NN * 32 + 255) / 256, 256, 0, stream>>>(x, xb, NN * 32);

    // ---- CSR (dst-sorted incoming edges, self-loop at slot 0 of each segment) ----
    hipMemsetAsync(cnt, 0, (size_t)NN * 4, stream);
    count_edges<<<(EE + 255) / 256, 256, 0, stream>>>(e_dst, cnt);
    scan_kernel<<<1, 1024, 0, stream>>>(cnt, indptr, cursor, esrc);
    scatter_edges<<<(EE + 255) / 256, 256, 0, stream>>>(e_src, e_dst, cursor, esrc);

    // ---- independent output gathers ----
    gather_feats<<<(NN * 32 + 255) / 256, 256, 0, stream>>>(Bf, Tf, voc, batch, out);

    const int MB = NPAD / 128;   // 157
    const int SB = NPAD / 64;    // 314
    const int NB4 = (NN + 3) / 4;

    // ---- GAT layer 0 (h-GEMM with fused logits) ----
    mfma_gemm<64, unsigned short, true><<<4 * MB, 256, 0, stream>>>(xb, 128, w0t, 128, hbuf, 256, NN, 128, nullptr, 0, 4, as0, ad0, al, ar);
    aggregate_kernel<<<NB4, 256, 0, stream>>>(hbuf, al, ar, indptr, esrc, b0, z + 0, 1536);
    mfma_gemm<64, unsigned short, false><<<4 * MB, 256, 0, stream>>>(z + 0, 1536, wmt, 256, z + 256, 1536, NN, 256, fcmax_b, 1, 4, nullptr, nullptr, nullptr, nullptr);

    // ---- GAT layer 1 ----
    mfma_gemm<64, unsigned short, true><<<4 * MB, 256, 0, stream>>>(z + 256, 1536, w1t, 256, hbuf, 256, NN, 256, nullptr, 0, 4, as1, ad1, al, ar);
    aggregate_kernel<<<NB4, 256, 0, stream>>>(hbuf, al, ar, indptr, esrc, b1, z + 512, 1536);
    mfma_gemm<64, unsigned short, false><<<4 * MB, 256, 0, stream>>>(z + 512, 1536, wmt, 256, z + 768, 1536, NN, 256, fcmax_b, 1, 4, nullptr, nullptr, nullptr, nullptr);

    // ---- GAT layer 2 ----
    mfma_gemm<64, unsigned short, true><<<4 * MB, 256, 0, stream>>>(z + 768, 1536, w2t, 256, hbuf, 256, NN, 256, nullptr, 0, 4, as2, ad2, al, ar);
    aggregate_kernel<<<NB4, 256, 0, stream>>>(hbuf, al, ar, indptr, esrc, b2, z + 1024, 1536);
    mfma_gemm<64, unsigned short, false><<<4 * MB, 256, 0, stream>>>(z + 1024, 1536, wmt, 256, z + 1280, 1536, NN, 256, fcmax_b, 1, 4, nullptr, nullptr, nullptr, nullptr);

    // ---- MLP head ----
    mfma_gemm<64, unsigned short, false><<<8 * MB, 256, 0, stream>>>(z, 1536, f1t, 1536, z1, 512, NN, 1536, fc1_b, 1, 8, nullptr, nullptr, nullptr, nullptr);
    mfma_gemm<64, unsigned short, false><<<2 * MB, 256, 0, stream>>>(z1, 512, f2t, 512, h2, 128, NN, 512, fc2_b, 1, 2, nullptr, nullptr, nullptr, nullptr);
    sshot_gemm<128, float><<<1 * SB, 256, 0, stream>>>(h2, 128, f3t, 128, out + (size_t)2 * NN * 128, 64, NN, fc3_b, 0, 1);
}

// Round 12
// 316.864 us; speedup vs baseline: 1.1914x; 1.0107x over previous
//
#include <hip/hip_runtime.h>
#include <math.h>

#define NN 20000
#define NPAD 20096   // 157*128 = 314*64: staging reads never go OOB
#define EE 320000
#define ET (EE + NN)

typedef __attribute__((ext_vector_type(8))) short bf16x8;
typedef __attribute__((ext_vector_type(4))) float f32x4;
typedef __attribute__((ext_vector_type(4))) unsigned short us4;
typedef __attribute__((ext_vector_type(8))) unsigned short us8;
typedef __attribute__((ext_vector_type(4))) float fx4;

__device__ inline unsigned short f2bf(float f) {
    union { float f; unsigned u; } x; x.f = f;
    unsigned u = x.u;
    return (unsigned short)((u + 0x7FFF + ((u >> 16) & 1)) >> 16);
}
__device__ inline float bf2f(unsigned short u) {
    union { unsigned u; float f; } x; x.u = (unsigned)u << 16; return x.f;
}

__device__ inline void storeC(float* C, size_t idx, float v) { C[idx] = v; }
__device__ inline void storeC(unsigned short* C, size_t idx, float v) { C[idx] = f2bf(v); }

// async 16B/lane global -> LDS (linear dest: wave base + lane*16)
__device__ inline void gload_lds16(const void* g, void* l) {
    __builtin_amdgcn_global_load_lds(
        (const __attribute__((address_space(1))) unsigned int*)g,
        (__attribute__((address_space(3))) unsigned int*)l, 16, 0, 0);
}

// bijective XCD-chunked swizzle (m204)
__device__ inline int xcd_swz(int orig, int nwg) {
    int q = nwg >> 3, r = nwg & 7;
    int xcd = orig & 7, loc = orig >> 3;
    return (xcd < r ? xcd * (q + 1) : r * (q + 1) + (xcd - r) * q) + loc;
}

// ---------------- pre-pass: batched weight transpose+convert (1 launch) ----------------
__device__ inline void transpose_tile(const float* __restrict__ W, unsigned short* __restrict__ Wt,
                                      int K, int N, int lb) {
    __shared__ float t[32][33];
    int kb = K >> 5;
    int k0 = (lb % kb) * 32, n0 = (lb / kb) * 32;
    int c = threadIdx.x & 31, r8 = threadIdx.x >> 5;
    #pragma unroll
    for (int i = 0; i < 4; i++)
        t[r8 + i * 8][c] = W[(size_t)(k0 + r8 + i * 8) * N + n0 + c];
    __syncthreads();
    #pragma unroll
    for (int i = 0; i < 4; i++)
        Wt[(size_t)(n0 + r8 + i * 8) * K + k0 + c] = f2bf(t[c][r8 + i * 8]);
}

__global__ __launch_bounds__(256) void transpose_all(
    const float* s0, unsigned short* d0,   // 128x256  -> 32 blocks
    const float* s1, unsigned short* d1,   // 256x256  -> 64
    const float* s2, unsigned short* d2,   // 256x256  -> 64
    const float* s3, unsigned short* d3,   // 256x256  -> 64
    const float* s4, unsigned short* d4,   // 1536x512 -> 768
    const float* s5, unsigned short* d5,   // 512x128  -> 64
    const float* s6, unsigned short* d6)   // 128x64   -> 8
{
    int b = blockIdx.x;
    if      (b < 32)   transpose_tile(s0, d0, 128, 256, b);
    else if (b < 96)   transpose_tile(s1, d1, 256, 256, b - 32);
    else if (b < 160)  transpose_tile(s2, d2, 256, 256, b - 96);
    else if (b < 224)  transpose_tile(s3, d3, 256, 256, b - 160);
    else if (b < 992)  transpose_tile(s4, d4, 1536, 512, b - 224);
    else if (b < 1056) transpose_tile(s5, d5, 512, 128, b - 992);
    else               transpose_tile(s6, d6, 128, 64, b - 1056);
}

__global__ void cvt_bf16_v4(const float* __restrict__ in, unsigned short* __restrict__ out, int n4) {
    int i = blockIdx.x * blockDim.x + threadIdx.x;
    if (i < n4) {
        fx4 v = *(const fx4*)(in + (size_t)i * 4);
        us4 s;
        #pragma unroll
        for (int j = 0; j < 4; j++) s[j] = f2bf(v[j]);
        *(us4*)(out + (size_t)i * 4) = s;
    }
}

// ---------------- CSR construction ----------------
__global__ void count_edges(const int* dst, int* cnt) {
    int e = blockIdx.x * blockDim.x + threadIdx.x;
    if (e < EE) atomicAdd(&cnt[dst[e]], 1);
}

__global__ void scan_kernel(const int* cnt, int* indptr, int* cursor, int* esrc) {
    __shared__ int part[1024];
    int tid = threadIdx.x;
    const int CH = 20;
    int base = tid * CH;
    int sum = 0;
    for (int i = 0; i < CH; i++) {
        int idx = base + i;
        if (idx < NN) sum += cnt[idx] + 1;
    }
    part[tid] = sum;
    __syncthreads();
    for (int off = 1; off < 1024; off <<= 1) {
        int v = (tid >= off) ? part[tid - off] : 0;
        __syncthreads();
        part[tid] += v;
        __syncthreads();
    }
    int run = (tid == 0) ? 0 : part[tid - 1];
    for (int i = 0; i < CH; i++) {
        int idx = base + i;
        if (idx < NN) {
            indptr[idx] = run;
            esrc[run] = idx;       // self-loop in slot 0
            cursor[idx] = run + 1;
            run += cnt[idx] + 1;
        }
    }
    if (tid == 1023) indptr[NN] = run;
}

__global__ void scatter_edges(const int* src, const int* dst, int* cursor, int* esrc) {
    int e = blockIdx.x * blockDim.x + threadIdx.x;
    if (e < EE) {
        int pos = atomicAdd(&cursor[dst[e]], 1);
        esrc[pos] = src[e];
    }
}

// ---------------- single-shot GEMM (fc3 only: N=64, K=128) ----------------
template <int KTOT, typename TC>
__global__ __launch_bounds__(256) void sshot_gemm(
    const unsigned short* __restrict__ A, int lda,
    const unsigned short* __restrict__ Bt, int ldbt,
    TC* __restrict__ C, int ldc,
    int M, const float* __restrict__ bias, int relu, int nwgx)
{
    constexpr int LPR = KTOT / 8;
    constexpr int RPC = 512 / KTOT;
    constexpr int NCH = KTOT / 8;
    constexpr int NCHW = NCH / 4;
    constexpr int KC = KTOT / 32;
    __shared__ unsigned short Als[64 * KTOT];
    __shared__ unsigned short Bls[64 * KTOT];

    int swz = xcd_swz(blockIdx.x, gridDim.x);
    int bx = swz % nwgx, by = swz / nwgx;
    int row0 = by * 64, col0 = bx * 64;

    int tid = threadIdx.x;
    int lane = tid & 63, w = tid >> 6;
    int ric = lane / LPR, slot = lane % LPR;

    #pragma unroll
    for (int i = 0; i < NCHW; i++) {
        int ch = w * NCHW + i;
        int r = ch * RPC + ric;
        gload_lds16(A + (size_t)(row0 + r) * lda + ((slot ^ (r & 7)) << 3),
                    &Als[ch * 512 + lane * 8]);
    }
    #pragma unroll
    for (int i = 0; i < NCHW; i++) {
        int ch = w * NCHW + i;
        int r = ch * RPC + ric;
        gload_lds16(Bt + (size_t)(col0 + r) * ldbt + ((slot ^ (r & 7)) << 3),
                    &Bls[ch * 512 + lane * 8]);
    }
    __syncthreads();

    f32x4 acc[4];
    #pragma unroll
    for (int j = 0; j < 4; j++) acc[j] = (f32x4){0.f, 0.f, 0.f, 0.f};

    #pragma unroll
    for (int kc = 0; kc < KC; kc++) {
        int ks = (kc << 2) + (lane >> 4);
        int ra = (w << 4) + (lane & 15);
        bf16x8 af = *(bf16x8*)&Als[ra * KTOT + ((ks ^ (ra & 7)) << 3)];
        #pragma unroll
        for (int j = 0; j < 4; j++) {
            int rb = (j << 4) + (lane & 15);
            bf16x8 bf = *(bf16x8*)&Bls[rb * KTOT + ((ks ^ (rb & 7)) << 3)];
            acc[j] = __builtin_amdgcn_mfma_f32_16x16x32_bf16(af, bf, acc[j], 0, 0, 0);
        }
    }

    #pragma unroll
    for (int rr = 0; rr < 4; rr++) {
        int row = row0 + (w << 4) + ((lane >> 4) << 2) + rr;
        if (row >= M) continue;
        #pragma unroll
        for (int j = 0; j < 4; j++) {
            int col = col0 + j * 16 + (lane & 15);
            float v = acc[j][rr] + (bias ? bias[col] : 0.f);
            if (relu) v = fmaxf(v, 0.f);
            storeC(C, (size_t)row * ldc + col, v);
        }
    }
}

// ---------------- fc1 GEMM: BM=128, BN=128, BK=32, 2x2 waves, depth-2 counted vmcnt ----------------
// 32KB LDS -> 5 blocks/CU; 8 ds_read vs 16 MFMA per K-step.
// Swizzle: slot ^= (row>>1)&3 (4 slots/row), same involution on stage-src and read.
__global__ __launch_bounds__(256) void mfma_gemm32(
    const unsigned short* __restrict__ A, int lda,
    const unsigned short* __restrict__ Bt, int ldbt,
    unsigned short* __restrict__ C, int ldc,
    int M, int K, const float* __restrict__ bias, int nwgx)
{
    __shared__ unsigned short Als[2][128 * 32];
    __shared__ unsigned short Bls[2][128 * 32];

    int swz = xcd_swz(blockIdx.x, gridDim.x);
    int bx = swz % nwgx, by = swz / nwgx;
    int tid = threadIdx.x, lane = tid & 63, w = tid >> 6;
    int wm = w >> 1, wn = w & 1;
    int row0 = by * 128, col0 = bx * 128;

    // staging: 1KB chunk = 16 rows x 32 elems; lane -> (ric=lane>>2, slot=lane&3)
    int ric = lane >> 2;
    int scol = ((lane & 3) ^ ((ric >> 1) & 3)) << 3;   // inverse-swizzled source col

    f32x4 acc[4][4];
    #pragma unroll
    for (int i = 0; i < 4; i++)
        #pragma unroll
        for (int j = 0; j < 4; j++) acc[i][j] = (f32x4){0.f, 0.f, 0.f, 0.f};

    auto stage = [&](int buf, int k0) {
        #pragma unroll
        for (int i = 0; i < 2; i++) {
            int ch = w * 2 + i;
            int r = (ch << 4) + ric;
            gload_lds16(A + (size_t)(row0 + r) * lda + k0 + scol,
                        &Als[buf][(ch << 9) + (lane << 3)]);
        }
        #pragma unroll
        for (int i = 0; i < 2; i++) {
            int ch = w * 2 + i;
            int r = (ch << 4) + ric;
            gload_lds16(Bt + (size_t)(col0 + r) * ldbt + k0 + scol,
                        &Bls[buf][(ch << 9) + (lane << 3)]);
        }
    };

    auto compute = [&](int buf) {
        int ks = lane >> 4;
        bf16x8 af[4], bfr[4];
        #pragma unroll
        for (int i = 0; i < 4; i++) {
            int rr = wm * 64 + (i << 4) + (lane & 15);
            af[i] = *(bf16x8*)&Als[buf][(rr << 5) + ((ks ^ ((rr >> 1) & 3)) << 3)];
        }
        #pragma unroll
        for (int j = 0; j < 4; j++) {
            int rr = wn * 64 + (j << 4) + (lane & 15);
            bfr[j] = *(bf16x8*)&Bls[buf][(rr << 5) + ((ks ^ ((rr >> 1) & 3)) << 3)];
        }
        #pragma unroll
        for (int i = 0; i < 4; i++)
            #pragma unroll
            for (int j = 0; j < 4; j++)
                acc[i][j] = __builtin_amdgcn_mfma_f32_16x16x32_bf16(af[i], bfr[j], acc[i][j], 0, 0, 0);
    };

    int NT = K >> 5;
    stage(0, 0);
    stage(1, 32);
    for (int t = 0; t < NT; ++t) {
        if (t < NT - 1)
            asm volatile("s_waitcnt vmcnt(4)" ::: "memory");
        else
            asm volatile("s_waitcnt vmcnt(0)" ::: "memory");
        __builtin_amdgcn_s_barrier();
        compute(t & 1);
        if (t + 2 < NT) {
            __builtin_amdgcn_s_barrier();
            stage(t & 1, (t + 2) << 5);
        }
    }

    #pragma unroll
    for (int i = 0; i < 4; i++) {
        #pragma unroll
        for (int rr = 0; rr < 4; rr++) {
            int row = row0 + wm * 64 + (i << 4) + ((lane >> 4) << 2) + rr;
            if (row >= M) continue;
            #pragma unroll
            for (int j = 0; j < 4; j++) {
                int col = col0 + wn * 64 + j * 16 + (lane & 15);
                float v = fmaxf(acc[i][j][rr] + bias[col], 0.f);
                C[(size_t)row * ldc + col] = f2bf(v);
            }
        }
    }
}

// ---------------- pipelined GEMM: depth-2 counted vmcnt; optional fused logits ----------------
template <int BN, typename TC, bool LOGITS>
__global__ __launch_bounds__(256) void mfma_gemm(
    const unsigned short* __restrict__ A, int lda,
    const unsigned short* __restrict__ Bt, int ldbt,
    TC* __restrict__ C, int ldc,
    int M, int K,
    const float* __restrict__ bias, int relu, int nwgx,
    const float* __restrict__ asrc, const float* __restrict__ adst,
    float* __restrict__ al, float* __restrict__ ar)
{
    constexpr int BM = 128, BK = 64;
    constexpr int WNW = (BN >= 128) ? 2 : 1;
    constexpr int WMW = 4 / WNW;
    constexpr int RW = BM / WMW;
    constexpr int NI = RW / 16;
    constexpr int NJ = 4;
    constexpr int NCHB = BN / 8;
    constexpr int PER_STAGE = 4 + NCHB / 4;
    __shared__ unsigned short Als[2][BM * BK];
    __shared__ unsigned short Bls[2][BN * BK];

    int swz = xcd_swz(blockIdx.x, gridDim.x);
    int bx = swz % nwgx, by = swz / nwgx;

    int tid = threadIdx.x;
    int lane = tid & 63, w = tid >> 6;
    int wm = (WNW == 2) ? (w >> 1) : w;
    int wn = (WNW == 2) ? (w & 1) : 0;
    int row0 = by * BM, col0 = bx * BN;

    int lr = lane >> 3;
    int scol = ((lane & 7) ^ lr) << 3;

    f32x4 acc[NI][NJ];
    #pragma unroll
    for (int i = 0; i < NI; i++)
        #pragma unroll
        for (int j = 0; j < NJ; j++) acc[i][j] = (f32x4){0.f, 0.f, 0.f, 0.f};

    auto stage = [&](int buf, int k0) {
        #pragma unroll
        for (int i = 0; i < 4; i++) {
            int ch = (w << 2) + i;
            gload_lds16(A + (size_t)(row0 + (ch << 3) + lr) * lda + k0 + scol,
                        &Als[buf][(ch << 9) + (lane << 3)]);
        }
        #pragma unroll
        for (int i = 0; i < NCHB / 4; i++) {
            int ch = w * (NCHB / 4) + i;
            gload_lds16(Bt + (size_t)(col0 + (ch << 3) + lr) * ldbt + k0 + scol,
                        &Bls[buf][(ch << 9) + (lane << 3)]);
        }
    };

    auto compute = [&](int buf) {
        #pragma unroll
        for (int kc = 0; kc < 2; kc++) {
            int ks = (kc << 2) + (lane >> 4);
            bf16x8 af[NI];
            #pragma unroll
            for (int i = 0; i < NI; i++) {
                int rr = wm * RW + (i << 4) + (lane & 15);
                af[i] = *(bf16x8*)&Als[buf][(rr << 6) + ((ks ^ (rr & 7)) << 3)];
            }
            bf16x8 bfr[NJ];
            #pragma unroll
            for (int j = 0; j < NJ; j++) {
                int rr = wn * 64 + (j << 4) + (lane & 15);
                bfr[j] = *(bf16x8*)&Bls[buf][(rr << 6) + ((ks ^ (rr & 7)) << 3)];
            }
            #pragma unroll
            for (int i = 0; i < NI; i++)
                #pragma unroll
                for (int j = 0; j < NJ; j++)
                    acc[i][j] = __builtin_amdgcn_mfma_f32_16x16x32_bf16(af[i], bfr[j], acc[i][j], 0, 0, 0);
        }
    };

    int NT = K >> 6;
    stage(0, 0);
    stage(1, BK);
    for (int t = 0; t < NT; ++t) {
        if (t < NT - 1)
            asm volatile("s_waitcnt vmcnt(%0)" :: "i"(PER_STAGE) : "memory");
        else
            asm volatile("s_waitcnt vmcnt(0)" ::: "memory");
        __builtin_amdgcn_s_barrier();
        compute(t & 1);
        if (t + 2 < NT) {
            __builtin_amdgcn_s_barrier();
            stage(t & 1, (t + 2) << 6);
        }
    }

    if constexpr (LOGITS) {
        int hh = col0 >> 6;
        float as_j[NJ], ad_j[NJ];
        #pragma unroll
        for (int j = 0; j < NJ; j++) {
            int cl = j * 16 + (lane & 15);
            as_j[j] = asrc[hh * 64 + cl];
            ad_j[j] = adst[hh * 64 + cl];
        }
        #pragma unroll
        for (int i = 0; i < NI; i++) {
            #pragma unroll
            for (int rr = 0; rr < 4; rr++) {
                int row = row0 + wm * RW + (i << 4) + ((lane >> 4) << 2) + rr;
                float ps = 0.f, pd = 0.f;
                #pragma unroll
                for (int j = 0; j < NJ; j++) {
                    float v = acc[i][j][rr];
                    ps += v * as_j[j];
                    pd += v * ad_j[j];
                    if (row < M) {
                        int col = col0 + j * 16 + (lane & 15);
                        storeC(C, (size_t)row * ldc + col, v);
                    }
                }
                #pragma unroll
                for (int off = 8; off; off >>= 1) {
                    ps += __shfl_xor(ps, off);
                    pd += __shfl_xor(pd, off);
                }
                if ((lane & 15) == 0 && row < M) {
                    al[row * 4 + hh] = ps;
                    ar[row * 4 + hh] = pd;
                }
            }
        }
    } else {
        #pragma unroll
        for (int i = 0; i < NI; i++) {
            #pragma unroll
            for (int rr = 0; rr < 4; rr++) {
                int row = row0 + wm * RW + (i << 4) + ((lane >> 4) << 2) + rr;
                if (row >= M) continue;
                #pragma unroll
                for (int j = 0; j < NJ; j++) {
                    int col = col0 + wn * 64 + j * 16 + (lane & 15);
                    float v = acc[i][j][rr] + (bias ? bias[col] : 0.f);
                    if (relu) v = fmaxf(v, 0.f);
                    storeC(C, (size_t)row * ldc + col, v);
                }
            }
        }
    }
}

// ---------------- GAT aggregation: wave per node, 4 ch/lane, unroll-4, NO max pass ----------------
__global__ __launch_bounds__(256) void aggregate_kernel(
    const unsigned short* __restrict__ hbuf,
    const float* __restrict__ al, const float* __restrict__ ar,
    const int* __restrict__ indptr, const int* __restrict__ esrc,
    const float* __restrict__ bias,
    unsigned short* __restrict__ out, int ldo)
{
    int w = threadIdx.x >> 6;
    int n = blockIdx.x * 4 + w;
    if (n >= NN) return;
    int lane = threadIdx.x & 63;
    int myh = lane >> 4;
    int c4 = lane * 4;
    int beg = indptr[n], end = indptr[n + 1];

    float arh = ar[(size_t)n * 4 + myh];

    float ssum = 0.f;
    fx4 acc = (fx4){0.f, 0.f, 0.f, 0.f};
    int j = beg;
    for (; j + 4 <= end; j += 4) {
        int s0 = esrc[j], s1 = esrc[j + 1], s2 = esrc[j + 2], s3 = esrc[j + 3];
        us4 h0 = *(const us4*)&hbuf[(size_t)s0 * 256 + c4];
        us4 h1 = *(const us4*)&hbuf[(size_t)s1 * 256 + c4];
        us4 h2 = *(const us4*)&hbuf[(size_t)s2 * 256 + c4];
        us4 h3 = *(const us4*)&hbuf[(size_t)s3 * 256 + c4];
        float a0 = al[(size_t)s0 * 4 + myh];
        float a1 = al[(size_t)s1 * 4 + myh];
        float a2 = al[(size_t)s2 * 4 + myh];
        float a3 = al[(size_t)s3 * 4 + myh];
        float e0 = a0 + arh; e0 = e0 > 0.f ? e0 : 0.2f * e0;
        float e1 = a1 + arh; e1 = e1 > 0.f ? e1 : 0.2f * e1;
        float e2 = a2 + arh; e2 = e2 > 0.f ? e2 : 0.2f * e2;
        float e3 = a3 + arh; e3 = e3 > 0.f ? e3 : 0.2f * e3;
        float x0 = __expf(e0), x1 = __expf(e1);
        float x2 = __expf(e2), x3 = __expf(e3);
        ssum += x0 + x1 + x2 + x3;
        #pragma unroll
        for (int k = 0; k < 4; k++)
            acc[k] += x0 * bf2f(h0[k]) + x1 * bf2f(h1[k])
                    + x2 * bf2f(h2[k]) + x3 * bf2f(h3[k]);
    }
    for (; j < end; j++) {
        int s = esrc[j];
        us4 hv = *(const us4*)&hbuf[(size_t)s * 256 + c4];
        float a = al[(size_t)s * 4 + myh];
        float e = a + arh; e = e > 0.f ? e : 0.2f * e;
        float ex = __expf(e);
        ssum += ex;
        #pragma unroll
        for (int k = 0; k < 4; k++) acc[k] += ex * bf2f(hv[k]);
    }

    float inv = 1.f / (ssum + 1e-16f);
    us4 o;
    #pragma unroll
    for (int k = 0; k < 4; k++) o[k] = f2bf(acc[k] * inv + bias[c4 + k]);
    *(us4*)&out[(size_t)n * ldo + c4] = o;
}

// ---------------- output gathers (vectorized) ----------------
__global__ void gather_feats(const float* __restrict__ Bf, const float* __restrict__ Tf,
                             const int* __restrict__ voc, const int* __restrict__ batch,
                             float* __restrict__ out)
{
    int i = blockIdx.x * blockDim.x + threadIdx.x;
    if (i < NN * 32) {
        int n = i >> 5, c4 = (i & 31) * 4;
        int t = voc[n];
        *(fx4*)&out[(size_t)n * 128 + c4] = *(const fx4*)&Bf[(size_t)t * 128 + c4];
        *(fx4*)&out[(size_t)NN * 128 + (size_t)n * 128 + c4] = *(const fx4*)&Tf[(size_t)t * 128 + c4];
    }
    if (i < NN) out[(size_t)NN * 128 * 2 + (size_t)NN * 64 + i] = (float)batch[i];
}

// ---------------- host-side orchestration ----------------
extern "C" void kernel_launch(void* const* d_in, const int* in_sizes, int n_in,
                              void* d_out, int out_size, void* d_ws, size_t ws_size,
                              hipStream_t stream) {
    const float* x     = (const float*)d_in[0];
    const int*   ei    = (const int*)d_in[1];
    const int*   batch = (const int*)d_in[2];
    const int*   voc   = (const int*)d_in[3];
    const float* Bf    = (const float*)d_in[4];
    const float* Tf    = (const float*)d_in[5];
    const float* W0    = (const float*)d_in[6];
    const float* as0   = (const float*)d_in[7];
    const float* ad0   = (const float*)d_in[8];
    const float* b0    = (const float*)d_in[9];
    const float* W1    = (const float*)d_in[10];
    const float* as1   = (const float*)d_in[11];
    const float* ad1   = (const float*)d_in[12];
    const float* b1    = (const float*)d_in[13];
    const float* W2    = (const float*)d_in[14];
    const float* as2   = (const float*)d_in[15];
    const float* ad2   = (const float*)d_in[16];
    const float* b2    = (const float*)d_in[17];
    const float* fcmax_w = (const float*)d_in[18];
    const float* fcmax_b = (const float*)d_in[19];
    const float* fc1_w = (const float*)d_in[20];
    const float* fc1_b = (const float*)d_in[21];
    const float* fc2_w = (const float*)d_in[22];
    const float* fc2_b = (const float*)d_in[23];
    const float* fc3_w = (const float*)d_in[24];
    const float* fc3_b = (const float*)d_in[25];
    float* out = (float*)d_out;

    char* p = (char*)d_ws;
    unsigned short* xb  = (unsigned short*)p; p += (size_t)NPAD * 128 * 2;
    unsigned short* hbuf= (unsigned short*)p; p += (size_t)NN * 256 * 2;
    unsigned short* z   = (unsigned short*)p; p += (size_t)NPAD * 1536 * 2;
    unsigned short* z1  = (unsigned short*)p; p += (size_t)NPAD * 512 * 2;
    unsigned short* h2  = (unsigned short*)p; p += (size_t)NPAD * 128 * 2;
    unsigned short* w0t = (unsigned short*)p; p += (size_t)128 * 256 * 2;
    unsigned short* w1t = (unsigned short*)p; p += (size_t)256 * 256 * 2;
    unsigned short* w2t = (unsigned short*)p; p += (size_t)256 * 256 * 2;
    unsigned short* wmt = (unsigned short*)p; p += (size_t)256 * 256 * 2;
    unsigned short* f1t = (unsigned short*)p; p += (size_t)1536 * 512 * 2;
    unsigned short* f2t = (unsigned short*)p; p += (size_t)512 * 128 * 2;
    unsigned short* f3t = (unsigned short*)p; p += (size_t)128 * 64 * 2;
    float* al   = (float*)p; p += (size_t)NN * 4 * 4;
    float* ar   = (float*)p; p += (size_t)NN * 4 * 4;
    int* cnt    = (int*)p;   p += (size_t)NN * 4;
    int* cursor = (int*)p;   p += (size_t)NN * 4;
    int* esrc   = (int*)p;   p += (size_t)ET * 4;
    int* indptr = (int*)p;   p += (size_t)(NN + 1) * 4;

    const int* e_src = ei;
    const int* e_dst = ei + EE;

    // ---- pre-pass: weights -> bf16 transposed (1 launch), x -> bf16 ----
    transpose_all<<<1064, 256, 0, stream>>>(W0, w0t, W1, w1t, W2, w2t, fcmax_w, wmt,
                                            fc1_w, f1t, fc2_w, f2t, fc3_w, f3t);
    cvt_bf16_v4<<<(NN * 32 + 255) / 256, 256, 0, stream>>>(x, xb, NN * 32);

    // ---- CSR (dst-sorted incoming edges, self-loop at slot 0 of each segment) ----
    hipMemsetAsync(cnt, 0, (size_t)NN * 4, stream);
    count_edges<<<(EE + 255) / 256, 256, 0, stream>>>(e_dst, cnt);
    scan_kernel<<<1, 1024, 0, stream>>>(cnt, indptr, cursor, esrc);
    scatter_edges<<<(EE + 255) / 256, 256, 0, stream>>>(e_src, e_dst, cursor, esrc);

    // ---- independent output gathers ----
    gather_feats<<<(NN * 32 + 255) / 256, 256, 0, stream>>>(Bf, Tf, voc, batch, out);

    const int MB = NPAD / 128;   // 157
    const int SB = NPAD / 64;    // 314
    const int NB4 = (NN + 3) / 4;

    // ---- GAT layer 0 (h-GEMM with fused logits) ----
    mfma_gemm<64, unsigned short, true><<<4 * MB, 256, 0, stream>>>(xb, 128, w0t, 128, hbuf, 256, NN, 128, nullptr, 0, 4, as0, ad0, al, ar);
    aggregate_kernel<<<NB4, 256, 0, stream>>>(hbuf, al, ar, indptr, esrc, b0, z + 0, 1536);
    mfma_gemm<64, unsigned short, false><<<4 * MB, 256, 0, stream>>>(z + 0, 1536, wmt, 256, z + 256, 1536, NN, 256, fcmax_b, 1, 4, nullptr, nullptr, nullptr, nullptr);

    // ---- GAT layer 1 ----
    mfma_gemm<64, unsigned short, true><<<4 * MB, 256, 0, stream>>>(z + 256, 1536, w1t, 256, hbuf, 256, NN, 256, nullptr, 0, 4, as1, ad1, al, ar);
    aggregate_kernel<<<NB4, 256, 0, stream>>>(hbuf, al, ar, indptr, esrc, b1, z + 512, 1536);
    mfma_gemm<64, unsigned short, false><<<4 * MB, 256, 0, stream>>>(z + 512, 1536, wmt, 256, z + 768, 1536, NN, 256, fcmax_b, 1, 4, nullptr, nullptr, nullptr, nullptr);

    // ---- GAT layer 2 ----
    mfma_gemm<64, unsigned short, true><<<4 * MB, 256, 0, stream>>>(z + 768, 1536, w2t, 256, hbuf, 256, NN, 256, nullptr, 0, 4, as2, ad2, al, ar);
    aggregate_kernel<<<NB4, 256, 0, stream>>>(hbuf, al, ar, indptr, esrc, b2, z + 1024, 1536);
    mfma_gemm<64, unsigned short, false><<<4 * MB, 256, 0, stream>>>(z + 1024, 1536, wmt, 256, z + 1280, 1536, NN, 256, fcmax_b, 1, 4, nullptr, nullptr, nullptr, nullptr);

    // ---- MLP head ----
    mfma_gemm32<<<4 * MB, 256, 0, stream>>>(z, 1536, f1t, 1536, z1, 512, NN, 1536, fc1_b, 4);
    mfma_gemm<64, unsigned short, false><<<2 * MB, 256, 0, stream>>>(z1, 512, f2t, 512, h2, 128, NN, 512, fc2_b, 1, 2, nullptr, nullptr, nullptr, nullptr);
    sshot_gemm<128, float><<<1 * SB, 256, 0, stream>>>(h2, 128, f3t, 128, out + (size_t)2 * NN * 128, 64, NN, fc3_b, 0, 1);
}

// Round 13
// 307.154 us; speedup vs baseline: 1.2290x; 1.0316x over previous
//
#include <hip/hip_runtime.h>
#include <math.h>

#define NN 20000
#define NPAD 20096   // 157*128 = 314*64: staging reads never go OOB
#define EE 320000
#define ET (EE + NN)

typedef __attribute__((ext_vector_type(8))) short bf16x8;
typedef __attribute__((ext_vector_type(4))) float f32x4;
typedef __attribute__((ext_vector_type(4))) unsigned short us4;
typedef __attribute__((ext_vector_type(8))) unsigned short us8;
typedef __attribute__((ext_vector_type(4))) float fx4;

__device__ inline unsigned short f2bf(float f) {
    union { float f; unsigned u; } x; x.f = f;
    unsigned u = x.u;
    return (unsigned short)((u + 0x7FFF + ((u >> 16) & 1)) >> 16);
}
__device__ inline float bf2f(unsigned short u) {
    union { unsigned u; float f; } x; x.u = (unsigned)u << 16; return x.f;
}

__device__ inline void storeC(float* C, size_t idx, float v) { C[idx] = v; }
__device__ inline void storeC(unsigned short* C, size_t idx, float v) { C[idx] = f2bf(v); }

// async 16B/lane global -> LDS (linear dest: wave base + lane*16)
__device__ inline void gload_lds16(const void* g, void* l) {
    __builtin_amdgcn_global_load_lds(
        (const __attribute__((address_space(1))) unsigned int*)g,
        (__attribute__((address_space(3))) unsigned int*)l, 16, 0, 0);
}

// bijective XCD-chunked swizzle (m204)
__device__ inline int xcd_swz(int orig, int nwg) {
    int q = nwg >> 3, r = nwg & 7;
    int xcd = orig & 7, loc = orig >> 3;
    return (xcd < r ? xcd * (q + 1) : r * (q + 1) + (xcd - r) * q) + loc;
}

// ---------------- pre-pass: batched weight transpose+convert + x convert (1 launch) ----------------
__device__ inline void transpose_tile(const float* __restrict__ W, unsigned short* __restrict__ Wt,
                                      int K, int N, int lb) {
    __shared__ float t[32][33];
    int kb = K >> 5;
    int k0 = (lb % kb) * 32, n0 = (lb / kb) * 32;
    int c = threadIdx.x & 31, r8 = threadIdx.x >> 5;
    #pragma unroll
    for (int i = 0; i < 4; i++)
        t[r8 + i * 8][c] = W[(size_t)(k0 + r8 + i * 8) * N + n0 + c];
    __syncthreads();
    #pragma unroll
    for (int i = 0; i < 4; i++)
        Wt[(size_t)(n0 + r8 + i * 8) * K + k0 + c] = f2bf(t[c][r8 + i * 8]);
}

__global__ __launch_bounds__(256) void transpose_all(
    const float* s0, unsigned short* d0,   // 128x256  -> 32 blocks
    const float* s1, unsigned short* d1,   // 256x256  -> 64
    const float* s2, unsigned short* d2,   // 256x256  -> 64
    const float* s3, unsigned short* d3,   // 256x256  -> 64
    const float* s4, unsigned short* d4,   // 1536x512 -> 768
    const float* s5, unsigned short* d5,   // 512x128  -> 64
    const float* s6, unsigned short* d6,   // 128x64   -> 8
    const float* xf, unsigned short* xb)   // x convert -> 2500 blocks
{
    int b = blockIdx.x;
    if      (b < 32)   transpose_tile(s0, d0, 128, 256, b);
    else if (b < 96)   transpose_tile(s1, d1, 256, 256, b - 32);
    else if (b < 160)  transpose_tile(s2, d2, 256, 256, b - 96);
    else if (b < 224)  transpose_tile(s3, d3, 256, 256, b - 160);
    else if (b < 992)  transpose_tile(s4, d4, 1536, 512, b - 224);
    else if (b < 1056) transpose_tile(s5, d5, 512, 128, b - 992);
    else if (b < 1064) transpose_tile(s6, d6, 128, 64, b - 1056);
    else {
        int i = (b - 1064) * 256 + threadIdx.x;
        if (i < NN * 32) {
            fx4 v = *(const fx4*)(xf + (size_t)i * 4);
            us4 s;
            #pragma unroll
            for (int j = 0; j < 4; j++) s[j] = f2bf(v[j]);
            *(us4*)(xb + (size_t)i * 4) = s;
        }
    }
}

// ---------------- CSR construction ----------------
__global__ void count_edges(const int* dst, int* cnt) {
    int e = blockIdx.x * blockDim.x + threadIdx.x;
    if (e < EE) atomicAdd(&cnt[dst[e]], 1);
}

__global__ void scan_kernel(const int* cnt, int* indptr, int* cursor, int* esrc) {
    __shared__ int part[1024];
    int tid = threadIdx.x;
    const int CH = 20;
    int base = tid * CH;
    int sum = 0;
    for (int i = 0; i < CH; i++) {
        int idx = base + i;
        if (idx < NN) sum += cnt[idx] + 1;
    }
    part[tid] = sum;
    __syncthreads();
    for (int off = 1; off < 1024; off <<= 1) {
        int v = (tid >= off) ? part[tid - off] : 0;
        __syncthreads();
        part[tid] += v;
        __syncthreads();
    }
    int run = (tid == 0) ? 0 : part[tid - 1];
    for (int i = 0; i < CH; i++) {
        int idx = base + i;
        if (idx < NN) {
            indptr[idx] = run;
            esrc[run] = idx;       // self-loop in slot 0
            cursor[idx] = run + 1;
            run += cnt[idx] + 1;
        }
    }
    if (tid == 1023) indptr[NN] = run;
}

__global__ void scatter_edges(const int* src, const int* dst, int* cursor, int* esrc) {
    int e = blockIdx.x * blockDim.x + threadIdx.x;
    if (e < EE) {
        int pos = atomicAdd(&cursor[dst[e]], 1);
        esrc[pos] = src[e];
    }
}

// ---------------- single-shot GEMM (fc3 only: N=64, K=128) ----------------
template <int KTOT, typename TC>
__global__ __launch_bounds__(256) void sshot_gemm(
    const unsigned short* __restrict__ A, int lda,
    const unsigned short* __restrict__ Bt, int ldbt,
    TC* __restrict__ C, int ldc,
    int M, const float* __restrict__ bias, int relu, int nwgx)
{
    constexpr int LPR = KTOT / 8;
    constexpr int RPC = 512 / KTOT;
    constexpr int NCH = KTOT / 8;
    constexpr int NCHW = NCH / 4;
    constexpr int KC = KTOT / 32;
    __shared__ unsigned short Als[64 * KTOT];
    __shared__ unsigned short Bls[64 * KTOT];

    int swz = xcd_swz(blockIdx.x, gridDim.x);
    int bx = swz % nwgx, by = swz / nwgx;
    int row0 = by * 64, col0 = bx * 64;

    int tid = threadIdx.x;
    int lane = tid & 63, w = tid >> 6;
    int ric = lane / LPR, slot = lane % LPR;

    #pragma unroll
    for (int i = 0; i < NCHW; i++) {
        int ch = w * NCHW + i;
        int r = ch * RPC + ric;
        gload_lds16(A + (size_t)(row0 + r) * lda + ((slot ^ (r & 7)) << 3),
                    &Als[ch * 512 + lane * 8]);
    }
    #pragma unroll
    for (int i = 0; i < NCHW; i++) {
        int ch = w * NCHW + i;
        int r = ch * RPC + ric;
        gload_lds16(Bt + (size_t)(col0 + r) * ldbt + ((slot ^ (r & 7)) << 3),
                    &Bls[ch * 512 + lane * 8]);
    }
    __syncthreads();

    f32x4 acc[4];
    #pragma unroll
    for (int j = 0; j < 4; j++) acc[j] = (f32x4){0.f, 0.f, 0.f, 0.f};

    #pragma unroll
    for (int kc = 0; kc < KC; kc++) {
        int ks = (kc << 2) + (lane >> 4);
        int ra = (w << 4) + (lane & 15);
        bf16x8 af = *(bf16x8*)&Als[ra * KTOT + ((ks ^ (ra & 7)) << 3)];
        #pragma unroll
        for (int j = 0; j < 4; j++) {
            int rb = (j << 4) + (lane & 15);
            bf16x8 bf = *(bf16x8*)&Bls[rb * KTOT + ((ks ^ (rb & 7)) << 3)];
            acc[j] = __builtin_amdgcn_mfma_f32_16x16x32_bf16(af, bf, acc[j], 0, 0, 0);
        }
    }

    #pragma unroll
    for (int rr = 0; rr < 4; rr++) {
        int row = row0 + (w << 4) + ((lane >> 4) << 2) + rr;
        if (row >= M) continue;
        #pragma unroll
        for (int j = 0; j < 4; j++) {
            int col = col0 + j * 16 + (lane & 15);
            float v = acc[j][rr] + (bias ? bias[col] : 0.f);
            if (relu) v = fmaxf(v, 0.f);
            storeC(C, (size_t)row * ldc + col, v);
        }
    }
}

// ---------------- fc1 GEMM: BM=128, BN=128, BK=32, 2x2 waves, depth-2 counted vmcnt ----------------
__global__ __launch_bounds__(256) void mfma_gemm32(
    const unsigned short* __restrict__ A, int lda,
    const unsigned short* __restrict__ Bt, int ldbt,
    unsigned short* __restrict__ C, int ldc,
    int M, int K, const float* __restrict__ bias, int nwgx)
{
    __shared__ unsigned short Als[2][128 * 32];
    __shared__ unsigned short Bls[2][128 * 32];

    int swz = xcd_swz(blockIdx.x, gridDim.x);
    int bx = swz % nwgx, by = swz / nwgx;
    int tid = threadIdx.x, lane = tid & 63, w = tid >> 6;
    int wm = w >> 1, wn = w & 1;
    int row0 = by * 128, col0 = bx * 128;

    int ric = lane >> 2;
    int scol = ((lane & 3) ^ ((ric >> 1) & 3)) << 3;

    f32x4 acc[4][4];
    #pragma unroll
    for (int i = 0; i < 4; i++)
        #pragma unroll
        for (int j = 0; j < 4; j++) acc[i][j] = (f32x4){0.f, 0.f, 0.f, 0.f};

    auto stage = [&](int buf, int k0) {
        #pragma unroll
        for (int i = 0; i < 2; i++) {
            int ch = w * 2 + i;
            int r = (ch << 4) + ric;
            gload_lds16(A + (size_t)(row0 + r) * lda + k0 + scol,
                        &Als[buf][(ch << 9) + (lane << 3)]);
        }
        #pragma unroll
        for (int i = 0; i < 2; i++) {
            int ch = w * 2 + i;
            int r = (ch << 4) + ric;
            gload_lds16(Bt + (size_t)(col0 + r) * ldbt + k0 + scol,
                        &Bls[buf][(ch << 9) + (lane << 3)]);
        }
    };

    auto compute = [&](int buf) {
        int ks = lane >> 4;
        bf16x8 af[4], bfr[4];
        #pragma unroll
        for (int i = 0; i < 4; i++) {
            int rr = wm * 64 + (i << 4) + (lane & 15);
            af[i] = *(bf16x8*)&Als[buf][(rr << 5) + ((ks ^ ((rr >> 1) & 3)) << 3)];
        }
        #pragma unroll
        for (int j = 0; j < 4; j++) {
            int rr = wn * 64 + (j << 4) + (lane & 15);
            bfr[j] = *(bf16x8*)&Bls[buf][(rr << 5) + ((ks ^ ((rr >> 1) & 3)) << 3)];
        }
        #pragma unroll
        for (int i = 0; i < 4; i++)
            #pragma unroll
            for (int j = 0; j < 4; j++)
                acc[i][j] = __builtin_amdgcn_mfma_f32_16x16x32_bf16(af[i], bfr[j], acc[i][j], 0, 0, 0);
    };

    int NT = K >> 5;
    stage(0, 0);
    stage(1, 32);
    for (int t = 0; t < NT; ++t) {
        if (t < NT - 1)
            asm volatile("s_waitcnt vmcnt(4)" ::: "memory");
        else
            asm volatile("s_waitcnt vmcnt(0)" ::: "memory");
        __builtin_amdgcn_s_barrier();
        compute(t & 1);
        if (t + 2 < NT) {
            __builtin_amdgcn_s_barrier();
            stage(t & 1, (t + 2) << 5);
        }
    }

    #pragma unroll
    for (int i = 0; i < 4; i++) {
        #pragma unroll
        for (int rr = 0; rr < 4; rr++) {
            int row = row0 + wm * 64 + (i << 4) + ((lane >> 4) << 2) + rr;
            if (row >= M) continue;
            #pragma unroll
            for (int j = 0; j < 4; j++) {
                int col = col0 + wn * 64 + j * 16 + (lane & 15);
                float v = fmaxf(acc[i][j][rr] + bias[col], 0.f);
                C[(size_t)row * ldc + col] = f2bf(v);
            }
        }
    }
}

// ---------------- pipelined GEMM: depth-2 counted vmcnt; optional fused logits ----------------
// BM in {64,128}, BN=64: 4x1 waves, wave tile (BM/4) x 64.
template <int BM, int BN, typename TC, bool LOGITS>
__global__ __launch_bounds__(256) void mfma_gemm(
    const unsigned short* __restrict__ A, int lda,
    const unsigned short* __restrict__ Bt, int ldbt,
    TC* __restrict__ C, int ldc,
    int M, int K,
    const float* __restrict__ bias, int relu, int nwgx,
    const float* __restrict__ asrc, const float* __restrict__ adst,
    float* __restrict__ al, float* __restrict__ ar)
{
    constexpr int BK = 64;
    constexpr int RW = BM / 4;            // wave rows: 32 or 16
    constexpr int NI = RW / 16;           // 2 or 1
    constexpr int NJ = 4;
    constexpr int NCHA = BM / 8;
    constexpr int NCHB = BN / 8;
    constexpr int PER_STAGE = NCHA / 4 + NCHB / 4;
    __shared__ unsigned short Als[2][BM * BK];
    __shared__ unsigned short Bls[2][BN * BK];

    int swz = xcd_swz(blockIdx.x, gridDim.x);
    int bx = swz % nwgx, by = swz / nwgx;

    int tid = threadIdx.x;
    int lane = tid & 63, w = tid >> 6;
    int row0 = by * BM, col0 = bx * BN;

    int lr = lane >> 3;
    int scol = ((lane & 7) ^ lr) << 3;

    f32x4 acc[NI][NJ];
    #pragma unroll
    for (int i = 0; i < NI; i++)
        #pragma unroll
        for (int j = 0; j < NJ; j++) acc[i][j] = (f32x4){0.f, 0.f, 0.f, 0.f};

    auto stage = [&](int buf, int k0) {
        #pragma unroll
        for (int i = 0; i < NCHA / 4; i++) {
            int ch = w * (NCHA / 4) + i;
            gload_lds16(A + (size_t)(row0 + (ch << 3) + lr) * lda + k0 + scol,
                        &Als[buf][(ch << 9) + (lane << 3)]);
        }
        #pragma unroll
        for (int i = 0; i < NCHB / 4; i++) {
            int ch = w * (NCHB / 4) + i;
            gload_lds16(Bt + (size_t)(col0 + (ch << 3) + lr) * ldbt + k0 + scol,
                        &Bls[buf][(ch << 9) + (lane << 3)]);
        }
    };

    auto compute = [&](int buf) {
        #pragma unroll
        for (int kc = 0; kc < 2; kc++) {
            int ks = (kc << 2) + (lane >> 4);
            bf16x8 af[NI];
            #pragma unroll
            for (int i = 0; i < NI; i++) {
                int rr = w * RW + (i << 4) + (lane & 15);
                af[i] = *(bf16x8*)&Als[buf][(rr << 6) + ((ks ^ (rr & 7)) << 3)];
            }
            bf16x8 bfr[NJ];
            #pragma unroll
            for (int j = 0; j < NJ; j++) {
                int rr = (j << 4) + (lane & 15);
                bfr[j] = *(bf16x8*)&Bls[buf][(rr << 6) + ((ks ^ (rr & 7)) << 3)];
            }
            #pragma unroll
            for (int i = 0; i < NI; i++)
                #pragma unroll
                for (int j = 0; j < NJ; j++)
                    acc[i][j] = __builtin_amdgcn_mfma_f32_16x16x32_bf16(af[i], bfr[j], acc[i][j], 0, 0, 0);
        }
    };

    int NT = K >> 6;
    stage(0, 0);
    stage(1, BK);
    for (int t = 0; t < NT; ++t) {
        if (t < NT - 1)
            asm volatile("s_waitcnt vmcnt(%0)" :: "i"(PER_STAGE) : "memory");
        else
            asm volatile("s_waitcnt vmcnt(0)" ::: "memory");
        __builtin_amdgcn_s_barrier();
        compute(t & 1);
        if (t + 2 < NT) {
            __builtin_amdgcn_s_barrier();
            stage(t & 1, (t + 2) << 6);
        }
    }

    if constexpr (LOGITS) {
        int hh = col0 >> 6;
        float as_j[NJ], ad_j[NJ];
        #pragma unroll
        for (int j = 0; j < NJ; j++) {
            int cl = j * 16 + (lane & 15);
            as_j[j] = asrc[hh * 64 + cl];
            ad_j[j] = adst[hh * 64 + cl];
        }
        #pragma unroll
        for (int i = 0; i < NI; i++) {
            #pragma unroll
            for (int rr = 0; rr < 4; rr++) {
                int row = row0 + w * RW + (i << 4) + ((lane >> 4) << 2) + rr;
                float ps = 0.f, pd = 0.f;
                #pragma unroll
                for (int j = 0; j < NJ; j++) {
                    float v = acc[i][j][rr];
                    ps += v * as_j[j];
                    pd += v * ad_j[j];
                    if (row < M) {
                        int col = col0 + j * 16 + (lane & 15);
                        storeC(C, (size_t)row * ldc + col, v);
                    }
                }
                #pragma unroll
                for (int off = 8; off; off >>= 1) {
                    ps += __shfl_xor(ps, off);
                    pd += __shfl_xor(pd, off);
                }
                if ((lane & 15) == 0 && row < M) {
                    al[row * 4 + hh] = ps;
                    ar[row * 4 + hh] = pd;
                }
            }
        }
    } else {
        #pragma unroll
        for (int i = 0; i < NI; i++) {
            #pragma unroll
            for (int rr = 0; rr < 4; rr++) {
                int row = row0 + w * RW + (i << 4) + ((lane >> 4) << 2) + rr;
                if (row >= M) continue;
                #pragma unroll
                for (int j = 0; j < NJ; j++) {
                    int col = col0 + j * 16 + (lane & 15);
                    float v = acc[i][j][rr] + (bias ? bias[col] : 0.f);
                    if (relu) v = fmaxf(v, 0.f);
                    storeC(C, (size_t)row * ldc + col, v);
                }
            }
        }
    }
}

// ---------------- GAT aggregation: 2 nodes/wave (32 lanes/node), 8 ch/lane, unroll-4 ----------------
__global__ __launch_bounds__(256) void aggregate_kernel(
    const unsigned short* __restrict__ hbuf,
    const float* __restrict__ al, const float* __restrict__ ar,
    const int* __restrict__ indptr, const int* __restrict__ esrc,
    const float* __restrict__ bias,
    unsigned short* __restrict__ out, int ldo)
{
    int sub = threadIdx.x >> 5;         // half-wave id, 8 per block
    int n = blockIdx.x * 8 + sub;
    if (n >= NN) return;
    int lane = threadIdx.x & 31;
    int myh = lane >> 3;                // head (8 lanes per head)
    int c8 = lane * 8;                  // channel base
    int beg = indptr[n], end = indptr[n + 1];

    float arh = ar[(size_t)n * 4 + myh];

    float ssum = 0.f;
    float acc[8] = {};
    int j = beg;
    for (; j + 4 <= end; j += 4) {
        int s0 = esrc[j], s1 = esrc[j + 1], s2 = esrc[j + 2], s3 = esrc[j + 3];
        us8 h0 = *(const us8*)&hbuf[(size_t)s0 * 256 + c8];
        us8 h1 = *(const us8*)&hbuf[(size_t)s1 * 256 + c8];
        us8 h2 = *(const us8*)&hbuf[(size_t)s2 * 256 + c8];
        us8 h3 = *(const us8*)&hbuf[(size_t)s3 * 256 + c8];
        float a0 = al[(size_t)s0 * 4 + myh];
        float a1 = al[(size_t)s1 * 4 + myh];
        float a2 = al[(size_t)s2 * 4 + myh];
        float a3 = al[(size_t)s3 * 4 + myh];
        float e0 = a0 + arh; e0 = e0 > 0.f ? e0 : 0.2f * e0;
        float e1 = a1 + arh; e1 = e1 > 0.f ? e1 : 0.2f * e1;
        float e2 = a2 + arh; e2 = e2 > 0.f ? e2 : 0.2f * e2;
        float e3 = a3 + arh; e3 = e3 > 0.f ? e3 : 0.2f * e3;
        float x0 = __expf(e0), x1 = __expf(e1);
        float x2 = __expf(e2), x3 = __expf(e3);
        ssum += x0 + x1 + x2 + x3;
        #pragma unroll
        for (int k = 0; k < 8; k++)
            acc[k] += x0 * bf2f(h0[k]) + x1 * bf2f(h1[k])
                    + x2 * bf2f(h2[k]) + x3 * bf2f(h3[k]);
    }
    for (; j < end; j++) {
        int s = esrc[j];
        us8 hv = *(const us8*)&hbuf[(size_t)s * 256 + c8];
        float a = al[(size_t)s * 4 + myh];
        float e = a + arh; e = e > 0.f ? e : 0.2f * e;
        float ex = __expf(e);
        ssum += ex;
        #pragma unroll
        for (int k = 0; k < 8; k++) acc[k] += ex * bf2f(hv[k]);
    }

    float inv = 1.f / (ssum + 1e-16f);
    us8 o;
    #pragma unroll
    for (int k = 0; k < 8; k++) o[k] = f2bf(acc[k] * inv + bias[c8 + k]);
    *(us8*)&out[(size_t)n * ldo + c8] = o;
}

// ---------------- output gathers (vectorized) ----------------
__global__ void gather_feats(const float* __restrict__ Bf, const float* __restrict__ Tf,
                             const int* __restrict__ voc, const int* __restrict__ batch,
                             float* __restrict__ out)
{
    int i = blockIdx.x * blockDim.x + threadIdx.x;
    if (i < NN * 32) {
        int n = i >> 5, c4 = (i & 31) * 4;
        int t = voc[n];
        *(fx4*)&out[(size_t)n * 128 + c4] = *(const fx4*)&Bf[(size_t)t * 128 + c4];
        *(fx4*)&out[(size_t)NN * 128 + (size_t)n * 128 + c4] = *(const fx4*)&Tf[(size_t)t * 128 + c4];
    }
    if (i < NN) out[(size_t)NN * 128 * 2 + (size_t)NN * 64 + i] = (float)batch[i];
}

// ---------------- host-side orchestration ----------------
extern "C" void kernel_launch(void* const* d_in, const int* in_sizes, int n_in,
                              void* d_out, int out_size, void* d_ws, size_t ws_size,
                              hipStream_t stream) {
    const float* x     = (const float*)d_in[0];
    const int*   ei    = (const int*)d_in[1];
    const int*   batch = (const int*)d_in[2];
    const int*   voc   = (const int*)d_in[3];
    const float* Bf    = (const float*)d_in[4];
    const float* Tf    = (const float*)d_in[5];
    const float* W0    = (const float*)d_in[6];
    const float* as0   = (const float*)d_in[7];
    const float* ad0   = (const float*)d_in[8];
    const float* b0    = (const float*)d_in[9];
    const float* W1    = (const float*)d_in[10];
    const float* as1   = (const float*)d_in[11];
    const float* ad1   = (const float*)d_in[12];
    const float* b1    = (const float*)d_in[13];
    const float* W2    = (const float*)d_in[14];
    const float* as2   = (const float*)d_in[15];
    const float* ad2   = (const float*)d_in[16];
    const float* b2    = (const float*)d_in[17];
    const float* fcmax_w = (const float*)d_in[18];
    const float* fcmax_b = (const float*)d_in[19];
    const float* fc1_w = (const float*)d_in[20];
    const float* fc1_b = (const float*)d_in[21];
    const float* fc2_w = (const float*)d_in[22];
    const float* fc2_b = (const float*)d_in[23];
    const float* fc3_w = (const float*)d_in[24];
    const float* fc3_b = (const float*)d_in[25];
    float* out = (float*)d_out;

    char* p = (char*)d_ws;
    unsigned short* xb  = (unsigned short*)p; p += (size_t)NPAD * 128 * 2;
    unsigned short* hbuf= (unsigned short*)p; p += (size_t)NN * 256 * 2;
    unsigned short* z   = (unsigned short*)p; p += (size_t)NPAD * 1536 * 2;
    unsigned short* z1  = (unsigned short*)p; p += (size_t)NPAD * 512 * 2;
    unsigned short* h2  = (unsigned short*)p; p += (size_t)NPAD * 128 * 2;
    unsigned short* w0t = (unsigned short*)p; p += (size_t)128 * 256 * 2;
    unsigned short* w1t = (unsigned short*)p; p += (size_t)256 * 256 * 2;
    unsigned short* w2t = (unsigned short*)p; p += (size_t)256 * 256 * 2;
    unsigned short* wmt = (unsigned short*)p; p += (size_t)256 * 256 * 2;
    unsigned short* f1t = (unsigned short*)p; p += (size_t)1536 * 512 * 2;
    unsigned short* f2t = (unsigned short*)p; p += (size_t)512 * 128 * 2;
    unsigned short* f3t = (unsigned short*)p; p += (size_t)128 * 64 * 2;
    float* al   = (float*)p; p += (size_t)NN * 4 * 4;
    float* ar   = (float*)p; p += (size_t)NN * 4 * 4;
    int* cnt    = (int*)p;   p += (size_t)NN * 4;
    int* cursor = (int*)p;   p += (size_t)NN * 4;
    int* esrc   = (int*)p;   p += (size_t)ET * 4;
    int* indptr = (int*)p;   p += (size_t)(NN + 1) * 4;

    const int* e_src = ei;
    const int* e_dst = ei + EE;

    // ---- pre-pass: weights -> bf16 transposed + x -> bf16 (1 launch) ----
    transpose_all<<<1064 + 2500, 256, 0, stream>>>(W0, w0t, W1, w1t, W2, w2t, fcmax_w, wmt,
                                                   fc1_w, f1t, fc2_w, f2t, fc3_w, f3t, x, xb);

    // ---- CSR (dst-sorted incoming edges, self-loop at slot 0 of each segment) ----
    hipMemsetAsync(cnt, 0, (size_t)NN * 4, stream);
    count_edges<<<(EE + 255) / 256, 256, 0, stream>>>(e_dst, cnt);
    scan_kernel<<<1, 1024, 0, stream>>>(cnt, indptr, cursor, esrc);
    scatter_edges<<<(EE + 255) / 256, 256, 0, stream>>>(e_src, e_dst, cursor, esrc);

    // ---- independent output gathers ----
    gather_feats<<<(NN * 32 + 255) / 256, 256, 0, stream>>>(Bf, Tf, voc, batch, out);

    const int MB = NPAD / 128;   // 157
    const int SB = NPAD / 64;    // 314
    const int NB8 = (NN + 7) / 8;

    // ---- GAT layer 0 (h-GEMM with fused logits) ----
    mfma_gemm<64, 64, unsigned short, true><<<4 * SB, 256, 0, stream>>>(xb, 128, w0t, 128, hbuf, 256, NN, 128, nullptr, 0, 4, as0, ad0, al, ar);
    aggregate_kernel<<<NB8, 256, 0, stream>>>(hbuf, al, ar, indptr, esrc, b0, z + 0, 1536);
    mfma_gemm<64, 64, unsigned short, false><<<4 * SB, 256, 0, stream>>>(z + 0, 1536, wmt, 256, z + 256, 1536, NN, 256, fcmax_b, 1, 4, nullptr, nullptr, nullptr, nullptr);

    // ---- GAT layer 1 ----
    mfma_gemm<64, 64, unsigned short, true><<<4 * SB, 256, 0, stream>>>(z + 256, 1536, w1t, 256, hbuf, 256, NN, 256, nullptr, 0, 4, as1, ad1, al, ar);
    aggregate_kernel<<<NB8, 256, 0, stream>>>(hbuf, al, ar, indptr, esrc, b1, z + 512, 1536);
    mfma_gemm<64, 64, unsigned short, false><<<4 * SB, 256, 0, stream>>>(z + 512, 1536, wmt, 256, z + 768, 1536, NN, 256, fcmax_b, 1, 4, nullptr, nullptr, nullptr, nullptr);

    // ---- GAT layer 2 ----
    mfma_gemm<64, 64, unsigned short, true><<<4 * SB, 256, 0, stream>>>(z + 768, 1536, w2t, 256, hbuf, 256, NN, 256, nullptr, 0, 4, as2, ad2, al, ar);
    aggregate_kernel<<<NB8, 256, 0, stream>>>(hbuf, al, ar, indptr, esrc, b2, z + 1024, 1536);
    mfma_gemm<64, 64, unsigned short, false><<<4 * SB, 256, 0, stream>>>(z + 1024, 1536, wmt, 256, z + 1280, 1536, NN, 256, fcmax_b, 1, 4, nullptr, nullptr, nullptr, nullptr);

    // ---- MLP head ----
    mfma_gemm32<<<4 * MB, 256, 0, stream>>>(z, 1536, f1t, 1536, z1, 512, NN, 1536, fc1_b, 4);
    mfma_gemm<64, 64, unsigned short, false><<<2 * SB, 256, 0, stream>>>(z1, 512, f2t, 512, h2, 128, NN, 512, fc2_b, 1, 2, nullptr, nullptr, nullptr, nullptr);
    sshot_gemm<128, float><<<1 * SB, 256, 0, stream>>>(h2, 128, f3t, 128, out + (size_t)2 * NN * 128, 64, NN, fc3_b, 0, 1);
}